// Round 2
// baseline (126.264 us; speedup 1.0000x reference)
//
#include <hip/hip_runtime.h>
#include <math.h>

// CircleLoss fused — R10: R9's negatives-only main loop, with the two serial
// overheads restructured:
//  (1) no memset/bucket arrays: each simloss block scans tgt (32KB,
//      L2-resident) to build its class member list -> one fewer dispatch,
//      no bucket atomics in normalize.
//  (2) per-class positive correction moved AFTER the main loop: off the
//      per-block serial critical path, overlaps the 5-tile straggler tail.
// Main pipeline unchanged from R8/R9: upper-tri 128x128 tiles, pair
// scheduling, A panel in regs (2-term split bf16), B LDS-dbuf staged by
// stage waves, colbuf col-atomic combining, fence-free counter finalize.

#define NR    8192
#define DIMK  128
#define NT    64
#define NBLKS 512
#define MAXC  128

// e_n(s) = exp(64*max(s-0.25,0)^2) = 2^(u*u), u = max(fma(s,CE1,CE0),0)
// CE1 = 8*sqrt(log2(e)), CE0 = -0.25*CE1
#define CE1 9.6089795f
#define CE0 -2.4022449f

typedef __attribute__((ext_vector_type(8))) short short8;
typedef __attribute__((ext_vector_type(4))) float f32x4;
typedef __attribute__((address_space(3))) uint32_t lds_u32;
typedef const __attribute__((address_space(1))) uint32_t glb_u32;

__device__ __forceinline__ unsigned short bf16_rne(float f) {
  uint32_t u = __float_as_uint(f);
  u += 0x7FFFu + ((u >> 16) & 1u);
  return (unsigned short)(u >> 16);
}

__device__ __forceinline__ float fexp2(float x) {
#if __has_builtin(__builtin_amdgcn_exp2f)
  return __builtin_amdgcn_exp2f(x);
#else
  return exp2f(x);
#endif
}

// ws: xhi bf16[NR*DIMK] (2MB) | xlo (2MB) | gP f32[NR] | gN f32[NR] | counter

__global__ __launch_bounds__(256) void normalize_split_kernel(
    const float* __restrict__ x, unsigned short* __restrict__ xhi,
    unsigned short* __restrict__ xlo, float* __restrict__ gP,
    float* __restrict__ gN, int* __restrict__ counter) {
  if (blockIdx.x < 32)      gP[blockIdx.x * 256 + threadIdx.x] = 0.f;
  else if (blockIdx.x < 64) gN[(blockIdx.x - 32) * 256 + threadIdx.x] = 0.f;
  if (blockIdx.x == 64 && threadIdx.x == 0) *counter = 0;

  const int wave = threadIdx.x >> 6;
  const int lane = threadIdx.x & 63;
  const int row  = blockIdx.x * 4 + wave;
  const float2 v = ((const float2*)(x + (size_t)row * DIMK))[lane];
  float ss = v.x * v.x + v.y * v.y;
  #pragma unroll
  for (int s = 1; s < 64; s <<= 1) ss += __shfl_xor(ss, s);
  const float r = rsqrtf(ss);
  const float a = v.x * r, b = v.y * r;
  const unsigned short ha = bf16_rne(a), hb = bf16_rne(b);
  const float haf = __uint_as_float((uint32_t)ha << 16);
  const float hbf = __uint_as_float((uint32_t)hb << 16);
  ushort2 hi, lo;
  hi.x = ha; hi.y = hb;
  lo.x = bf16_rne(a - haf); lo.y = bf16_rne(b - hbf);
  ((ushort2*)xhi)[(size_t)row * 64 + lane] = hi;
  ((ushort2*)xlo)[(size_t)row * 64 + lane] = lo;
}

__global__ __launch_bounds__(512, 2) void simloss_kernel(
    const unsigned short* __restrict__ xhi, const unsigned short* __restrict__ xlo,
    const int* __restrict__ tgt, float* __restrict__ gP, float* __restrict__ gN,
    int* __restrict__ counter, float* __restrict__ out) {
  __shared__ unsigned short S[32768];   // 64KB: A stage, B dbuf, then corr scratch
  __shared__ float colbuf[2][4][128];   // 4KB, double-buffered col partials (N only)
  __shared__ float red[512];
  __shared__ int midx[MAXC];
  __shared__ int scnt;
  __shared__ int islast;

  const int tid  = threadIdx.x;
  const int wave = tid >> 6, lane = tid & 63;
  const int wy = wave & 3, wx = wave >> 2;   // frag grid: 4 row-waves x 2 col-waves
  const int q = lane >> 4, mcol = lane & 15;
  const bool isStage = (wy == 1) || (wy == 2);
  const bool isFlush = (wy == 0);
  const int srank = (wy - 1) + wx * 2;       // 0..3 for stage waves

  const int p  = blockIdx.x >> 4;            // pair index (0..31)
  const int b  = blockIdx.x & 15;
  const int n1 = NT - p;                     // tiles in panel1 (bi=p)
  const int t0 = (b * (NT + 1)) >> 4;        // 65 tiles per pair
  const int t1 = ((b + 1) * (NT + 1)) >> 4;
  const int ntile = t1 - t0;
  const int p2 = NT - 1 - p;                 // panel2 bi

  int cur_bi = (t0 < n1) ? p : p2;

  // ---- A staging (all waves). hi -> S[0..16K), lo -> S[16K..32K) ushorts ----
  auto stageA = [&](int bi) {
    const unsigned short* gh = xhi + (size_t)bi * 128 * DIMK;
    const unsigned short* gl = xlo + (size_t)bi * 128 * DIMK;
    #pragma unroll
    for (int g = 0; g < 4; ++g) {
      const int r  = wave * 16 + g * 4 + (lane >> 4);
      const int sc = (lane & 15) ^ (r & 15);   // XOR swizzle (R6-proven)
      __builtin_amdgcn_global_load_lds((glb_u32*)(gh + (size_t)r * DIMK + sc * 8),
          (lds_u32*)&S[(wave * 16 + g * 4) * 128], 16, 0, 0);
      __builtin_amdgcn_global_load_lds((glb_u32*)(gl + (size_t)r * DIMK + sc * 8),
          (lds_u32*)&S[16384 + (wave * 16 + g * 4) * 128], 16, 0, 0);
    }
  };
  // ---- B staging (stage waves only), 8 instrs each, 32KB tile ----
  auto stageB = [&](int bj, int buf) {
    const unsigned short* gb = xhi + (size_t)bj * 128 * DIMK;
    unsigned short* dst = &S[buf * 16384];
    #pragma unroll
    for (int g = 0; g < 8; ++g) {
      const int r  = srank * 32 + g * 4 + (lane >> 4);
      const int sc = (lane & 15) ^ (r & 15);
      __builtin_amdgcn_global_load_lds((glb_u32*)(gb + (size_t)r * DIMK + sc * 8),
          (lds_u32*)&dst[(srank * 32 + g * 4) * 128], 16, 0, 0);
    }
  };

  short8 Ah[2][4], Al[2][4];
  auto extractA = [&]() {
    #pragma unroll
    for (int fr = 0; fr < 2; ++fr) {
      const int r = wy * 32 + fr * 16 + mcol;
      #pragma unroll
      for (int ks = 0; ks < 4; ++ks) {
        const int pc = (ks * 4 + q) ^ mcol;
        Ah[fr][ks] = *(const short8*)&S[r * 128 + pc * 8];
        Al[fr][ks] = *(const short8*)&S[16384 + r * 128 + pc * 8];
      }
    }
  };

  float rowN[2][4] = {{0.f}};
  auto flushRows = [&](int bi_) {
    #pragma unroll
    for (int fr = 0; fr < 2; ++fr)
      #pragma unroll
      for (int rg = 0; rg < 4; ++rg) {
        float vn = rowN[fr][rg];
        #pragma unroll
        for (int m2 = 1; m2 < 16; m2 <<= 1) vn += __shfl_xor(vn, m2);
        if (mcol == 0)
          atomicAdd(&gN[bi_ * 128 + wy * 32 + fr * 16 + q * 4 + rg], vn);
      }
  };

  stageA(cur_bi);
  __syncthreads();            // A staged
  extractA();
  __builtin_amdgcn_s_waitcnt(49279);   // lgkm0: all frag reads done
  __builtin_amdgcn_s_barrier();        // -> S reusable as B buffers
  if (isStage) stageB((t0 < n1) ? p + t0 : p2 + (t0 - n1), 0);

  for (int tl = 0; tl < ntile; ++tl) {
    const int ix = t0 + tl;
    const int bi = (ix < n1) ? p : p2;
    const int bj = (ix < n1) ? p + ix : p2 + (ix - n1);

    if (bi != cur_bi) {       // panel switch (at most once per block)
      flushRows(cur_bi);
      cur_bi = bi;
      stageA(cur_bi);         // overwrites both B buffers (none pending)
      __syncthreads();
      extractA();
      #pragma unroll
      for (int fr = 0; fr < 2; ++fr)
        #pragma unroll
        for (int rg = 0; rg < 4; ++rg) rowN[fr][rg] = 0.f;
      __builtin_amdgcn_s_waitcnt(49279);
      __builtin_amdgcn_s_barrier();
      if (isStage) stageB(bj, tl & 1);
    }

    // start barrier: only stage waves drain their B loads (vm0+lgkm0 = 112)
    if (isStage) __builtin_amdgcn_s_waitcnt(112);
    __builtin_amdgcn_s_barrier();

    // prefetch next tile's B (same panel only; cross-panel handled above)
    if (tl + 1 < ntile) {
      const int ix2 = ix + 1;
      if ((ix2 < n1) == (ix < n1)) {
        const int bj2 = (ix2 < n1) ? p + ix2 : p2 + (ix2 - n1);
        if (isStage) stageB(bj2, (tl + 1) & 1);
      }
    }

    // ---- compute tile ----
    const unsigned short* Bb = &S[(tl & 1) * 16384];
    f32x4 acc[2][4];
    #pragma unroll
    for (int fr = 0; fr < 2; ++fr)
      #pragma unroll
      for (int fc = 0; fc < 4; ++fc)
        acc[fr][fc] = (f32x4){0.f, 0.f, 0.f, 0.f};
    #pragma unroll
    for (int ks = 0; ks < 4; ++ks) {
      short8 bh[4];
      #pragma unroll
      for (int fc = 0; fc < 4; ++fc) {
        const int rb = wx * 64 + fc * 16 + mcol;
        const int pc = (ks * 4 + q) ^ mcol;
        bh[fc] = *(const short8*)&Bb[rb * 128 + pc * 8];
      }
      #pragma unroll
      for (int fc = 0; fc < 4; ++fc) {
        acc[0][fc] = __builtin_amdgcn_mfma_f32_16x16x32_bf16(Ah[0][ks], bh[fc], acc[0][fc], 0, 0, 0);
        acc[1][fc] = __builtin_amdgcn_mfma_f32_16x16x32_bf16(Ah[1][ks], bh[fc], acc[1][fc], 0, 0, 0);
        acc[0][fc] = __builtin_amdgcn_mfma_f32_16x16x32_bf16(Al[0][ks], bh[fc], acc[0][fc], 0, 0, 0);
        acc[1][fc] = __builtin_amdgcn_mfma_f32_16x16x32_bf16(Al[1][ks], bh[fc], acc[1][fc], 0, 0, 0);
      }
    }

    // ---- epilogue: negatives-only. C layout col = mcol, row = q*4 + rg ----
    float cN[4] = {0.f, 0.f, 0.f, 0.f};
#define EPILOGUE(DIAG_)                                                      \
    {                                                                        \
      _Pragma("unroll")                                                      \
      for (int fr = 0; fr < 2; ++fr) {                                       \
        _Pragma("unroll")                                                    \
        for (int rg = 0; rg < 4; ++rg) {                                     \
          float vn = 0.f;                                                    \
          _Pragma("unroll")                                                  \
          for (int fc = 0; fc < 4; ++fc) {                                   \
            const float s = acc[fr][fc][rg];                                 \
            const float u = fmaxf(fmaf(s, CE1, CE0), 0.f);                   \
            float e = fexp2(u * u);                                          \
            if (DIAG_) {                                                     \
              const int rl = wy * 32 + fr * 16 + q * 4 + rg;                 \
              const int cl = wx * 64 + fc * 16 + mcol;                       \
              e = (rl == cl) ? 0.f : e;                                      \
            }                                                                \
            vn += e;                                                         \
            cN[fc] += e;                                                     \
          }                                                                  \
          rowN[fr][rg] += vn;                                                \
        }                                                                    \
      }                                                                      \
    }
    if (bj == bi) EPILOGUE(true) else EPILOGUE(false)
#undef EPILOGUE

    // col partials: q-reduce then ds_write (16 lanes per wave)
    #pragma unroll
    for (int fc = 0; fc < 4; ++fc) {
      cN[fc] += __shfl_xor(cN[fc], 16);
      cN[fc] += __shfl_xor(cN[fc], 32);
    }
    if (q == 0) {
      #pragma unroll
      for (int fc = 0; fc < 4; ++fc)
        colbuf[tl & 1][wy][wx * 64 + fc * 16 + mcol] = cN[fc];
    }
    __builtin_amdgcn_s_waitcnt(49279);   // lgkm0: colbuf writes visible
    __builtin_amdgcn_s_barrier();

    // flush waves: combine 4 wy slices, fire-and-forget device atomics
    if (isFlush && bj != bi) {
      const int col = wx * 64 + lane;
      float sn = 0.f;
      #pragma unroll
      for (int w = 0; w < 4; ++w) sn += colbuf[tl & 1][w][col];
      atomicAdd(&gN[bj * 128 + col], sn);
    }
  }
  flushRows(cur_bi);

  // ---- per-class positive correction (block == class), tail-scheduled ----
  // Independent of the main loop (atomics commute); running it here takes
  // it off the serial front of every block and overlaps straggler blocks.
  {
    if (tid == 0) scnt = 0;
    __syncthreads();           // also: S free (last tile's frag reads done)
    for (int v = tid; v < NR; v += 512) {
      if (tgt[v] == (int)blockIdx.x) {
        const int slot = atomicAdd(&scnt, 1);
        if (slot < MAXC) midx[slot] = v;
      }
    }
    __syncthreads();
    const int m = (scnt < MAXC) ? scnt : MAXC;
    float* Sf = (float*)S;                   // stride-129 f32 rows (bank-safe)
    for (int v = tid; v < m * 128; v += 512) {
      const int r = v >> 7, d = v & 127;
      const int row = midx[r];
      const float hi = __uint_as_float((uint32_t)xhi[(size_t)row * DIMK + d] << 16);
      const float lo = __uint_as_float((uint32_t)xlo[(size_t)row * DIMK + d] << 16);
      Sf[r * 129 + d] = hi + lo;
    }
    __syncthreads();
    for (int pr = tid; pr < m * m; pr += 512) {
      const int i = pr / m, j = pr - i * m;
      const float* vi = &Sf[i * 129];
      const float* vj = &Sf[j * 129];
      float s = 0.f;
      #pragma unroll 8
      for (int d = 0; d < 128; ++d) s = fmaf(vi[d], vj[d], s);
      const int gi = midx[i];
      // positive term: exp(64*max(1.25-s,0)*(s-0.75)); ap==0 -> exp(0)=1 (matches ref)
      const float ep = __expf(fmaxf(1.25f - s, 0.f) * fmaf(s, 64.f, -48.f));
      atomicAdd(&gP[gi], ep);
      if (i != j) {   // remove the e_n the main loop added for same-class pairs
        const float u = fmaxf(fmaf(s, CE1, CE0), 0.f);
        atomicAdd(&gN[gi], -fexp2(u * u));
      }
    }
  }

  // ---- fence-free last-block finalize (R4-proven) ----
  __builtin_amdgcn_s_waitcnt(0);   // all my atomics ack'd before counter bump
  __syncthreads();
  if (tid == 0) islast = (atomicAdd(counter, 1) == NBLKS - 1) ? 1 : 0;
  __syncthreads();
  if (islast) {
    float local = 0.f;
    #pragma unroll 1
    for (int bb = 0; bb < 2; ++bb) {
      const int base = bb * 4096 + tid * 8;
      float pv[8], nv[8];
      #pragma unroll
      for (int u = 0; u < 8; ++u) pv[u] = atomicAdd(&gP[base + u], 0.0f);
      #pragma unroll
      for (int u = 0; u < 8; ++u) nv[u] = atomicAdd(&gN[base + u], 0.0f);
      #pragma unroll
      for (int u = 0; u < 8; ++u) local += log1pf(pv[u] * nv[u]);
    }
    red[tid] = local;
    __syncthreads();
    for (int s2 = 256; s2 > 0; s2 >>= 1) {
      if (tid < s2) red[tid] += red[tid + s2];
      __syncthreads();
    }
    if (tid == 0) out[0] = red[0] / (float)NR;
  }
}

extern "C" void kernel_launch(void* const* d_in, const int* in_sizes, int n_in,
                              void* d_out, int out_size, void* d_ws, size_t ws_size,
                              hipStream_t stream) {
  const float* x  = (const float*)d_in[0];
  const int* tgt  = (const int*)d_in[1];
  float* out      = (float*)d_out;

  unsigned short* xhi = (unsigned short*)d_ws;
  unsigned short* xlo = xhi + (size_t)NR * DIMK;
  float* gP = (float*)((char*)d_ws + (size_t)NR * DIMK * 4);
  float* gN = gP + NR;
  int* counter = (int*)(gN + NR);

  normalize_split_kernel<<<NR / 4, 256, 0, stream>>>(x, xhi, xlo, gP, gN, counter);
  simloss_kernel<<<NBLKS, 512, 0, stream>>>(xhi, xlo, tgt, gP, gN, counter, out);
}

// Round 3
// 121.736 us; speedup vs baseline: 1.0372x; 1.0372x over previous
//
#include <hip/hip_runtime.h>
#include <math.h>

// CircleLoss fused — R11: R9's HEAD-scheduled per-class correction (proven
// 63.0us simloss) + R10's bucket-free tgt scan (no memset dispatch, no
// normalize atomics -> proven ~55us rest). Tail placement (R10) regressed
// because the end-of-kernel s_waitcnt(0) had to drain ~550 fresh scattered
// atomics from all 512 blocks simultaneously; at the head they retire under
// the main loop. Main pipeline unchanged from R8/R9/R10: upper-tri 128x128
// tiles, pair scheduling, A panel in regs (2-term split bf16), B LDS-dbuf
// staged by stage waves, negatives-only epilogue, colbuf col combining,
// fence-free counter finalize.

#define NR    8192
#define DIMK  128
#define NT    64
#define NBLKS 512
#define MAXC  64

// e_n(s) = exp(64*max(s-0.25,0)^2) = 2^(u*u), u = max(fma(s,CE1,CE0),0)
// CE1 = 8*sqrt(log2(e)), CE0 = -0.25*CE1
#define CE1 9.6089795f
#define CE0 -2.4022449f

typedef __attribute__((ext_vector_type(8))) short short8;
typedef __attribute__((ext_vector_type(4))) float f32x4;
typedef __attribute__((address_space(3))) uint32_t lds_u32;
typedef const __attribute__((address_space(1))) uint32_t glb_u32;

__device__ __forceinline__ unsigned short bf16_rne(float f) {
  uint32_t u = __float_as_uint(f);
  u += 0x7FFFu + ((u >> 16) & 1u);
  return (unsigned short)(u >> 16);
}

__device__ __forceinline__ float fexp2(float x) {
#if __has_builtin(__builtin_amdgcn_exp2f)
  return __builtin_amdgcn_exp2f(x);
#else
  return exp2f(x);
#endif
}

// ws: xhi bf16[NR*DIMK] (2MB) | xlo (2MB) | gP f32[NR] | gN f32[NR] | counter

__global__ __launch_bounds__(256) void normalize_split_kernel(
    const float* __restrict__ x, unsigned short* __restrict__ xhi,
    unsigned short* __restrict__ xlo, float* __restrict__ gP,
    float* __restrict__ gN, int* __restrict__ counter) {
  if (blockIdx.x < 32)      gP[blockIdx.x * 256 + threadIdx.x] = 0.f;
  else if (blockIdx.x < 64) gN[(blockIdx.x - 32) * 256 + threadIdx.x] = 0.f;
  if (blockIdx.x == 64 && threadIdx.x == 0) *counter = 0;

  const int wave = threadIdx.x >> 6;
  const int lane = threadIdx.x & 63;
  const int row  = blockIdx.x * 4 + wave;
  const float2 v = ((const float2*)(x + (size_t)row * DIMK))[lane];
  float ss = v.x * v.x + v.y * v.y;
  #pragma unroll
  for (int s = 1; s < 64; s <<= 1) ss += __shfl_xor(ss, s);
  const float r = rsqrtf(ss);
  const float a = v.x * r, b = v.y * r;
  const unsigned short ha = bf16_rne(a), hb = bf16_rne(b);
  const float haf = __uint_as_float((uint32_t)ha << 16);
  const float hbf = __uint_as_float((uint32_t)hb << 16);
  ushort2 hi, lo;
  hi.x = ha; hi.y = hb;
  lo.x = bf16_rne(a - haf); lo.y = bf16_rne(b - hbf);
  ((ushort2*)xhi)[(size_t)row * 64 + lane] = hi;
  ((ushort2*)xlo)[(size_t)row * 64 + lane] = lo;
}

__global__ __launch_bounds__(512, 2) void simloss_kernel(
    const unsigned short* __restrict__ xhi, const unsigned short* __restrict__ xlo,
    const int* __restrict__ tgt, float* __restrict__ gP, float* __restrict__ gN,
    int* __restrict__ counter, float* __restrict__ out) {
  __shared__ unsigned short S[32768];   // 64KB: corr scratch, A stage, B dbuf
  __shared__ float colbuf[2][4][128];   // 4KB, double-buffered col partials (N only)
  __shared__ float red[512];
  __shared__ int midx[MAXC];
  __shared__ int scnt;
  __shared__ int islast;

  const int tid  = threadIdx.x;
  const int wave = tid >> 6, lane = tid & 63;
  const int wy = wave & 3, wx = wave >> 2;   // frag grid: 4 row-waves x 2 col-waves
  const int q = lane >> 4, mcol = lane & 15;
  const bool isStage = (wy == 1) || (wy == 2);
  const bool isFlush = (wy == 0);
  const int srank = (wy - 1) + wx * 2;       // 0..3 for stage waves

  // ---- per-class positive correction (block == class), HEAD-scheduled ----
  // Atomics issued here retire under the main loop; the final s_waitcnt(0)
  // drain is then free (R9-proven). Member list built by scanning tgt
  // (32KB, L2-resident) -> no bucket arrays, no memset dispatch.
  {
    if (tid == 0) scnt = 0;
    __syncthreads();
    const int4* t4 = (const int4*)tgt;
    const int me = (int)blockIdx.x;
    for (int v = tid; v < NR / 4; v += 512) {   // 4 iterations
      const int4 tv = t4[v];
      const int base = v * 4;
      if (tv.x == me) { const int s_ = atomicAdd(&scnt, 1); if (s_ < MAXC) midx[s_] = base; }
      if (tv.y == me) { const int s_ = atomicAdd(&scnt, 1); if (s_ < MAXC) midx[s_] = base + 1; }
      if (tv.z == me) { const int s_ = atomicAdd(&scnt, 1); if (s_ < MAXC) midx[s_] = base + 2; }
      if (tv.w == me) { const int s_ = atomicAdd(&scnt, 1); if (s_ < MAXC) midx[s_] = base + 3; }
    }
    __syncthreads();
    const int m = (scnt < MAXC) ? scnt : MAXC;
    float* Sf = (float*)S;                   // stride-129 f32 rows (bank-safe)
    for (int v = tid; v < m * 32; v += 512) {
      const int r = v >> 5, c4 = v & 31;     // 4 dims per thread-iter
      const int row = midx[r];
      const ushort4 h = ((const ushort4*)(xhi + (size_t)row * DIMK))[c4];
      const ushort4 l = ((const ushort4*)(xlo + (size_t)row * DIMK))[c4];
      float* d = &Sf[r * 129 + c4 * 4];
      d[0] = __uint_as_float((uint32_t)h.x << 16) + __uint_as_float((uint32_t)l.x << 16);
      d[1] = __uint_as_float((uint32_t)h.y << 16) + __uint_as_float((uint32_t)l.y << 16);
      d[2] = __uint_as_float((uint32_t)h.z << 16) + __uint_as_float((uint32_t)l.z << 16);
      d[3] = __uint_as_float((uint32_t)h.w << 16) + __uint_as_float((uint32_t)l.w << 16);
    }
    __syncthreads();
    for (int pr = tid; pr < m * m; pr += 512) {
      const int i = pr / m, j = pr - i * m;
      const float* vi = &Sf[i * 129];
      const float* vj = &Sf[j * 129];
      float s = 0.f;
      #pragma unroll 8
      for (int d = 0; d < 128; ++d) s = fmaf(vi[d], vj[d], s);
      const int gi = midx[i];
      // positive term: exp(64*max(1.25-s,0)*(s-0.75)); ap==0 -> exp(0)=1 (matches ref)
      const float ep = __expf(fmaxf(1.25f - s, 0.f) * fmaf(s, 64.f, -48.f));
      atomicAdd(&gP[gi], ep);
      if (i != j) {   // remove the e_n the main loop will add for same-class pairs
        const float u = fmaxf(fmaf(s, CE1, CE0), 0.f);
        atomicAdd(&gN[gi], -fexp2(u * u));
      }
    }
    __syncthreads();   // S free for A staging
  }

  const int p  = blockIdx.x >> 4;            // pair index (0..31)
  const int b  = blockIdx.x & 15;
  const int n1 = NT - p;                     // tiles in panel1 (bi=p)
  const int t0 = (b * (NT + 1)) >> 4;        // 65 tiles per pair
  const int t1 = ((b + 1) * (NT + 1)) >> 4;
  const int ntile = t1 - t0;
  const int p2 = NT - 1 - p;                 // panel2 bi

  int cur_bi = (t0 < n1) ? p : p2;

  // ---- A staging (all waves). hi -> S[0..16K), lo -> S[16K..32K) ushorts ----
  auto stageA = [&](int bi) {
    const unsigned short* gh = xhi + (size_t)bi * 128 * DIMK;
    const unsigned short* gl = xlo + (size_t)bi * 128 * DIMK;
    #pragma unroll
    for (int g = 0; g < 4; ++g) {
      const int r  = wave * 16 + g * 4 + (lane >> 4);
      const int sc = (lane & 15) ^ (r & 15);   // XOR swizzle (R6-proven)
      __builtin_amdgcn_global_load_lds((glb_u32*)(gh + (size_t)r * DIMK + sc * 8),
          (lds_u32*)&S[(wave * 16 + g * 4) * 128], 16, 0, 0);
      __builtin_amdgcn_global_load_lds((glb_u32*)(gl + (size_t)r * DIMK + sc * 8),
          (lds_u32*)&S[16384 + (wave * 16 + g * 4) * 128], 16, 0, 0);
    }
  };
  // ---- B staging (stage waves only), 8 instrs each, 32KB tile ----
  auto stageB = [&](int bj, int buf) {
    const unsigned short* gb = xhi + (size_t)bj * 128 * DIMK;
    unsigned short* dst = &S[buf * 16384];
    #pragma unroll
    for (int g = 0; g < 8; ++g) {
      const int r  = srank * 32 + g * 4 + (lane >> 4);
      const int sc = (lane & 15) ^ (r & 15);
      __builtin_amdgcn_global_load_lds((glb_u32*)(gb + (size_t)r * DIMK + sc * 8),
          (lds_u32*)&dst[(srank * 32 + g * 4) * 128], 16, 0, 0);
    }
  };

  short8 Ah[2][4], Al[2][4];
  auto extractA = [&]() {
    #pragma unroll
    for (int fr = 0; fr < 2; ++fr) {
      const int r = wy * 32 + fr * 16 + mcol;
      #pragma unroll
      for (int ks = 0; ks < 4; ++ks) {
        const int pc = (ks * 4 + q) ^ mcol;
        Ah[fr][ks] = *(const short8*)&S[r * 128 + pc * 8];
        Al[fr][ks] = *(const short8*)&S[16384 + r * 128 + pc * 8];
      }
    }
  };

  float rowN[2][4] = {{0.f}};
  auto flushRows = [&](int bi_) {
    #pragma unroll
    for (int fr = 0; fr < 2; ++fr)
      #pragma unroll
      for (int rg = 0; rg < 4; ++rg) {
        float vn = rowN[fr][rg];
        #pragma unroll
        for (int m2 = 1; m2 < 16; m2 <<= 1) vn += __shfl_xor(vn, m2);
        if (mcol == 0)
          atomicAdd(&gN[bi_ * 128 + wy * 32 + fr * 16 + q * 4 + rg], vn);
      }
  };

  stageA(cur_bi);
  __syncthreads();            // A staged
  extractA();
  __builtin_amdgcn_s_waitcnt(49279);   // lgkm0: all frag reads done
  __builtin_amdgcn_s_barrier();        // -> S reusable as B buffers
  if (isStage) stageB((t0 < n1) ? p + t0 : p2 + (t0 - n1), 0);

  for (int tl = 0; tl < ntile; ++tl) {
    const int ix = t0 + tl;
    const int bi = (ix < n1) ? p : p2;
    const int bj = (ix < n1) ? p + ix : p2 + (ix - n1);

    if (bi != cur_bi) {       // panel switch (at most once per block)
      flushRows(cur_bi);
      cur_bi = bi;
      stageA(cur_bi);         // overwrites both B buffers (none pending)
      __syncthreads();
      extractA();
      #pragma unroll
      for (int fr = 0; fr < 2; ++fr)
        #pragma unroll
        for (int rg = 0; rg < 4; ++rg) rowN[fr][rg] = 0.f;
      __builtin_amdgcn_s_waitcnt(49279);
      __builtin_amdgcn_s_barrier();
      if (isStage) stageB(bj, tl & 1);
    }

    // start barrier: only stage waves drain their B loads (vm0+lgkm0 = 112)
    if (isStage) __builtin_amdgcn_s_waitcnt(112);
    __builtin_amdgcn_s_barrier();

    // prefetch next tile's B (same panel only; cross-panel handled above)
    if (tl + 1 < ntile) {
      const int ix2 = ix + 1;
      if ((ix2 < n1) == (ix < n1)) {
        const int bj2 = (ix2 < n1) ? p + ix2 : p2 + (ix2 - n1);
        if (isStage) stageB(bj2, (tl + 1) & 1);
      }
    }

    // ---- compute tile ----
    const unsigned short* Bb = &S[(tl & 1) * 16384];
    f32x4 acc[2][4];
    #pragma unroll
    for (int fr = 0; fr < 2; ++fr)
      #pragma unroll
      for (int fc = 0; fc < 4; ++fc)
        acc[fr][fc] = (f32x4){0.f, 0.f, 0.f, 0.f};
    #pragma unroll
    for (int ks = 0; ks < 4; ++ks) {
      short8 bh[4];
      #pragma unroll
      for (int fc = 0; fc < 4; ++fc) {
        const int rb = wx * 64 + fc * 16 + mcol;
        const int pc = (ks * 4 + q) ^ mcol;
        bh[fc] = *(const short8*)&Bb[rb * 128 + pc * 8];
      }
      #pragma unroll
      for (int fc = 0; fc < 4; ++fc) {
        acc[0][fc] = __builtin_amdgcn_mfma_f32_16x16x32_bf16(Ah[0][ks], bh[fc], acc[0][fc], 0, 0, 0);
        acc[1][fc] = __builtin_amdgcn_mfma_f32_16x16x32_bf16(Ah[1][ks], bh[fc], acc[1][fc], 0, 0, 0);
        acc[0][fc] = __builtin_amdgcn_mfma_f32_16x16x32_bf16(Al[0][ks], bh[fc], acc[0][fc], 0, 0, 0);
        acc[1][fc] = __builtin_amdgcn_mfma_f32_16x16x32_bf16(Al[1][ks], bh[fc], acc[1][fc], 0, 0, 0);
      }
    }

    // ---- epilogue: negatives-only. C layout col = mcol, row = q*4 + rg ----
    float cN[4] = {0.f, 0.f, 0.f, 0.f};
#define EPILOGUE(DIAG_)                                                      \
    {                                                                        \
      _Pragma("unroll")                                                      \
      for (int fr = 0; fr < 2; ++fr) {                                       \
        _Pragma("unroll")                                                    \
        for (int rg = 0; rg < 4; ++rg) {                                     \
          float vn = 0.f;                                                    \
          _Pragma("unroll")                                                  \
          for (int fc = 0; fc < 4; ++fc) {                                   \
            const float s = acc[fr][fc][rg];                                 \
            const float u = fmaxf(fmaf(s, CE1, CE0), 0.f);                   \
            float e = fexp2(u * u);                                          \
            if (DIAG_) {                                                     \
              const int rl = wy * 32 + fr * 16 + q * 4 + rg;                 \
              const int cl = wx * 64 + fc * 16 + mcol;                       \
              e = (rl == cl) ? 0.f : e;                                      \
            }                                                                \
            vn += e;                                                         \
            cN[fc] += e;                                                     \
          }                                                                  \
          rowN[fr][rg] += vn;                                                \
        }                                                                    \
      }                                                                      \
    }
    if (bj == bi) EPILOGUE(true) else EPILOGUE(false)
#undef EPILOGUE

    // col partials: q-reduce then ds_write (16 lanes per wave)
    #pragma unroll
    for (int fc = 0; fc < 4; ++fc) {
      cN[fc] += __shfl_xor(cN[fc], 16);
      cN[fc] += __shfl_xor(cN[fc], 32);
    }
    if (q == 0) {
      #pragma unroll
      for (int fc = 0; fc < 4; ++fc)
        colbuf[tl & 1][wy][wx * 64 + fc * 16 + mcol] = cN[fc];
    }
    __builtin_amdgcn_s_waitcnt(49279);   // lgkm0: colbuf writes visible
    __builtin_amdgcn_s_barrier();

    // flush waves: combine 4 wy slices, fire-and-forget device atomics
    if (isFlush && bj != bi) {
      const int col = wx * 64 + lane;
      float sn = 0.f;
      #pragma unroll
      for (int w = 0; w < 4; ++w) sn += colbuf[tl & 1][w][col];
      atomicAdd(&gN[bj * 128 + col], sn);
    }
  }
  flushRows(cur_bi);

  // ---- fence-free last-block finalize (R4-proven) ----
  __builtin_amdgcn_s_waitcnt(0);   // all my atomics ack'd before counter bump
  __syncthreads();
  if (tid == 0) islast = (atomicAdd(counter, 1) == NBLKS - 1) ? 1 : 0;
  __syncthreads();
  if (islast) {
    float local = 0.f;
    #pragma unroll 1
    for (int bb = 0; bb < 2; ++bb) {
      const int base = bb * 4096 + tid * 8;
      float pv[8], nv[8];
      #pragma unroll
      for (int u = 0; u < 8; ++u) pv[u] = atomicAdd(&gP[base + u], 0.0f);
      #pragma unroll
      for (int u = 0; u < 8; ++u) nv[u] = atomicAdd(&gN[base + u], 0.0f);
      #pragma unroll
      for (int u = 0; u < 8; ++u) local += log1pf(pv[u] * nv[u]);
    }
    red[tid] = local;
    __syncthreads();
    for (int s2 = 256; s2 > 0; s2 >>= 1) {
      if (tid < s2) red[tid] += red[tid + s2];
      __syncthreads();
    }
    if (tid == 0) out[0] = red[0] / (float)NR;
  }
}

extern "C" void kernel_launch(void* const* d_in, const int* in_sizes, int n_in,
                              void* d_out, int out_size, void* d_ws, size_t ws_size,
                              hipStream_t stream) {
  const float* x  = (const float*)d_in[0];
  const int* tgt  = (const int*)d_in[1];
  float* out      = (float*)d_out;

  unsigned short* xhi = (unsigned short*)d_ws;
  unsigned short* xlo = xhi + (size_t)NR * DIMK;
  float* gP = (float*)((char*)d_ws + (size_t)NR * DIMK * 4);
  float* gN = gP + NR;
  int* counter = (int*)(gN + NR);

  normalize_split_kernel<<<NR / 4, 256, 0, stream>>>(x, xhi, xlo, gP, gN, counter);
  simloss_kernel<<<NBLKS, 512, 0, stream>>>(xhi, xlo, tgt, gP, gN, counter, out);
}

// Round 4
// 117.154 us; speedup vs baseline: 1.0778x; 1.0391x over previous
//
#include <hip/hip_runtime.h>
#include <math.h>

// CircleLoss fused — R12: three-kernel structure. R11's simloss busy-time
// arithmetic didn't close (pipe-busy ~18us vs 64.6us wall, occupancy 15%
// vs structural 50%): the duration is dominated by a low-occupancy tail —
// every block's end-of-kernel s_waitcnt(0) atomic drain + all-block counter
// rendezvous + ONE block doing 16K L2 atomic-reads/log1p/9-barrier finalize
// while 255 CUs idle. Fix: move finalize to a third tiny kernel (dispatch
// boundary = full visibility of simloss atomics; no drain, no counter, no
// islast). simloss blocks now end right after their last flush.
// Main pipeline unchanged from R11: upper-tri 128x128 tiles, pair
// scheduling, A panel in regs (2-term split bf16), B LDS-dbuf staged by
// stage waves, negatives-only epilogue, head-scheduled per-class positive
// correction via tgt scan, colbuf col combining.

#define NR    8192
#define DIMK  128
#define NT    64
#define NBLKS 512
#define MAXC  64

// e_n(s) = exp(64*max(s-0.25,0)^2) = 2^(u*u), u = max(fma(s,CE1,CE0),0)
// CE1 = 8*sqrt(log2(e)), CE0 = -0.25*CE1
#define CE1 9.6089795f
#define CE0 -2.4022449f

typedef __attribute__((ext_vector_type(8))) short short8;
typedef __attribute__((ext_vector_type(4))) float f32x4;
typedef __attribute__((address_space(3))) uint32_t lds_u32;
typedef const __attribute__((address_space(1))) uint32_t glb_u32;

__device__ __forceinline__ unsigned short bf16_rne(float f) {
  uint32_t u = __float_as_uint(f);
  u += 0x7FFFu + ((u >> 16) & 1u);
  return (unsigned short)(u >> 16);
}

__device__ __forceinline__ float fexp2(float x) {
#if __has_builtin(__builtin_amdgcn_exp2f)
  return __builtin_amdgcn_exp2f(x);
#else
  return exp2f(x);
#endif
}

// ws: xhi bf16[NR*DIMK] (2MB) | xlo (2MB) | gP f32[NR] | gN f32[NR]

__global__ __launch_bounds__(256) void normalize_split_kernel(
    const float* __restrict__ x, unsigned short* __restrict__ xhi,
    unsigned short* __restrict__ xlo, float* __restrict__ gP,
    float* __restrict__ gN) {
  if (blockIdx.x < 32)      gP[blockIdx.x * 256 + threadIdx.x] = 0.f;
  else if (blockIdx.x < 64) gN[(blockIdx.x - 32) * 256 + threadIdx.x] = 0.f;

  const int wave = threadIdx.x >> 6;
  const int lane = threadIdx.x & 63;
  const int row  = blockIdx.x * 4 + wave;
  const float2 v = ((const float2*)(x + (size_t)row * DIMK))[lane];
  float ss = v.x * v.x + v.y * v.y;
  #pragma unroll
  for (int s = 1; s < 64; s <<= 1) ss += __shfl_xor(ss, s);
  const float r = rsqrtf(ss);
  const float a = v.x * r, b = v.y * r;
  const unsigned short ha = bf16_rne(a), hb = bf16_rne(b);
  const float haf = __uint_as_float((uint32_t)ha << 16);
  const float hbf = __uint_as_float((uint32_t)hb << 16);
  ushort2 hi, lo;
  hi.x = ha; hi.y = hb;
  lo.x = bf16_rne(a - haf); lo.y = bf16_rne(b - hbf);
  ((ushort2*)xhi)[(size_t)row * 64 + lane] = hi;
  ((ushort2*)xlo)[(size_t)row * 64 + lane] = lo;
}

__global__ __launch_bounds__(512, 2) void simloss_kernel(
    const unsigned short* __restrict__ xhi, const unsigned short* __restrict__ xlo,
    const int* __restrict__ tgt, float* __restrict__ gP, float* __restrict__ gN) {
  __shared__ unsigned short S[32768];   // 64KB: corr scratch, A stage, B dbuf
  __shared__ float colbuf[2][4][128];   // 4KB, double-buffered col partials (N only)
  __shared__ int midx[MAXC];
  __shared__ int scnt;

  const int tid  = threadIdx.x;
  const int wave = tid >> 6, lane = tid & 63;
  const int wy = wave & 3, wx = wave >> 2;   // frag grid: 4 row-waves x 2 col-waves
  const int q = lane >> 4, mcol = lane & 15;
  const bool isStage = (wy == 1) || (wy == 2);
  const bool isFlush = (wy == 0);
  const int srank = (wy - 1) + wx * 2;       // 0..3 for stage waves

  // ---- per-class positive correction (block == class), HEAD-scheduled ----
  // Atomics issued here retire under the main loop. Member list built by
  // scanning tgt (32KB, L2-resident).
  {
    if (tid == 0) scnt = 0;
    __syncthreads();
    const int4* t4 = (const int4*)tgt;
    const int me = (int)blockIdx.x;
    for (int v = tid; v < NR / 4; v += 512) {   // 4 iterations
      const int4 tv = t4[v];
      const int base = v * 4;
      if (tv.x == me) { const int s_ = atomicAdd(&scnt, 1); if (s_ < MAXC) midx[s_] = base; }
      if (tv.y == me) { const int s_ = atomicAdd(&scnt, 1); if (s_ < MAXC) midx[s_] = base + 1; }
      if (tv.z == me) { const int s_ = atomicAdd(&scnt, 1); if (s_ < MAXC) midx[s_] = base + 2; }
      if (tv.w == me) { const int s_ = atomicAdd(&scnt, 1); if (s_ < MAXC) midx[s_] = base + 3; }
    }
    __syncthreads();
    const int m = (scnt < MAXC) ? scnt : MAXC;
    float* Sf = (float*)S;                   // stride-129 f32 rows (bank-safe)
    for (int v = tid; v < m * 32; v += 512) {
      const int r = v >> 5, c4 = v & 31;     // 4 dims per thread-iter
      const int row = midx[r];
      const ushort4 h = ((const ushort4*)(xhi + (size_t)row * DIMK))[c4];
      const ushort4 l = ((const ushort4*)(xlo + (size_t)row * DIMK))[c4];
      float* d = &Sf[r * 129 + c4 * 4];
      d[0] = __uint_as_float((uint32_t)h.x << 16) + __uint_as_float((uint32_t)l.x << 16);
      d[1] = __uint_as_float((uint32_t)h.y << 16) + __uint_as_float((uint32_t)l.y << 16);
      d[2] = __uint_as_float((uint32_t)h.z << 16) + __uint_as_float((uint32_t)l.z << 16);
      d[3] = __uint_as_float((uint32_t)h.w << 16) + __uint_as_float((uint32_t)l.w << 16);
    }
    __syncthreads();
    for (int pr = tid; pr < m * m; pr += 512) {
      const int i = pr / m, j = pr - i * m;
      const float* vi = &Sf[i * 129];
      const float* vj = &Sf[j * 129];
      float s = 0.f;
      #pragma unroll 8
      for (int d = 0; d < 128; ++d) s = fmaf(vi[d], vj[d], s);
      const int gi = midx[i];
      // positive term: exp(64*max(1.25-s,0)*(s-0.75)); ap==0 -> exp(0)=1 (matches ref)
      const float ep = __expf(fmaxf(1.25f - s, 0.f) * fmaf(s, 64.f, -48.f));
      atomicAdd(&gP[gi], ep);
      if (i != j) {   // remove the e_n the main loop will add for same-class pairs
        const float u = fmaxf(fmaf(s, CE1, CE0), 0.f);
        atomicAdd(&gN[gi], -fexp2(u * u));
      }
    }
    __syncthreads();   // S free for A staging
  }

  const int p  = blockIdx.x >> 4;            // pair index (0..31)
  const int b  = blockIdx.x & 15;
  const int n1 = NT - p;                     // tiles in panel1 (bi=p)
  const int t0 = (b * (NT + 1)) >> 4;        // 65 tiles per pair
  const int t1 = ((b + 1) * (NT + 1)) >> 4;
  const int ntile = t1 - t0;
  const int p2 = NT - 1 - p;                 // panel2 bi

  int cur_bi = (t0 < n1) ? p : p2;

  // ---- A staging (all waves). hi -> S[0..16K), lo -> S[16K..32K) ushorts ----
  auto stageA = [&](int bi) {
    const unsigned short* gh = xhi + (size_t)bi * 128 * DIMK;
    const unsigned short* gl = xlo + (size_t)bi * 128 * DIMK;
    #pragma unroll
    for (int g = 0; g < 4; ++g) {
      const int r  = wave * 16 + g * 4 + (lane >> 4);
      const int sc = (lane & 15) ^ (r & 15);   // XOR swizzle (R6-proven)
      __builtin_amdgcn_global_load_lds((glb_u32*)(gh + (size_t)r * DIMK + sc * 8),
          (lds_u32*)&S[(wave * 16 + g * 4) * 128], 16, 0, 0);
      __builtin_amdgcn_global_load_lds((glb_u32*)(gl + (size_t)r * DIMK + sc * 8),
          (lds_u32*)&S[16384 + (wave * 16 + g * 4) * 128], 16, 0, 0);
    }
  };
  // ---- B staging (stage waves only), 8 instrs each, 32KB tile ----
  auto stageB = [&](int bj, int buf) {
    const unsigned short* gb = xhi + (size_t)bj * 128 * DIMK;
    unsigned short* dst = &S[buf * 16384];
    #pragma unroll
    for (int g = 0; g < 8; ++g) {
      const int r  = srank * 32 + g * 4 + (lane >> 4);
      const int sc = (lane & 15) ^ (r & 15);
      __builtin_amdgcn_global_load_lds((glb_u32*)(gb + (size_t)r * DIMK + sc * 8),
          (lds_u32*)&dst[(srank * 32 + g * 4) * 128], 16, 0, 0);
    }
  };

  short8 Ah[2][4], Al[2][4];
  auto extractA = [&]() {
    #pragma unroll
    for (int fr = 0; fr < 2; ++fr) {
      const int r = wy * 32 + fr * 16 + mcol;
      #pragma unroll
      for (int ks = 0; ks < 4; ++ks) {
        const int pc = (ks * 4 + q) ^ mcol;
        Ah[fr][ks] = *(const short8*)&S[r * 128 + pc * 8];
        Al[fr][ks] = *(const short8*)&S[16384 + r * 128 + pc * 8];
      }
    }
  };

  float rowN[2][4] = {{0.f}};
  auto flushRows = [&](int bi_) {
    #pragma unroll
    for (int fr = 0; fr < 2; ++fr)
      #pragma unroll
      for (int rg = 0; rg < 4; ++rg) {
        float vn = rowN[fr][rg];
        #pragma unroll
        for (int m2 = 1; m2 < 16; m2 <<= 1) vn += __shfl_xor(vn, m2);
        if (mcol == 0)
          atomicAdd(&gN[bi_ * 128 + wy * 32 + fr * 16 + q * 4 + rg], vn);
      }
  };

  stageA(cur_bi);
  __syncthreads();            // A staged
  extractA();
  __builtin_amdgcn_s_waitcnt(49279);   // lgkm0: all frag reads done
  __builtin_amdgcn_s_barrier();        // -> S reusable as B buffers
  if (isStage) stageB((t0 < n1) ? p + t0 : p2 + (t0 - n1), 0);

  for (int tl = 0; tl < ntile; ++tl) {
    const int ix = t0 + tl;
    const int bi = (ix < n1) ? p : p2;
    const int bj = (ix < n1) ? p + ix : p2 + (ix - n1);

    if (bi != cur_bi) {       // panel switch (at most once per block)
      flushRows(cur_bi);
      cur_bi = bi;
      stageA(cur_bi);         // overwrites both B buffers (none pending)
      __syncthreads();
      extractA();
      #pragma unroll
      for (int fr = 0; fr < 2; ++fr)
        #pragma unroll
        for (int rg = 0; rg < 4; ++rg) rowN[fr][rg] = 0.f;
      __builtin_amdgcn_s_waitcnt(49279);
      __builtin_amdgcn_s_barrier();
      if (isStage) stageB(bj, tl & 1);
    }

    // start barrier: only stage waves drain their B loads (vm0+lgkm0 = 112)
    if (isStage) __builtin_amdgcn_s_waitcnt(112);
    __builtin_amdgcn_s_barrier();

    // prefetch next tile's B (same panel only; cross-panel handled above)
    if (tl + 1 < ntile) {
      const int ix2 = ix + 1;
      if ((ix2 < n1) == (ix < n1)) {
        const int bj2 = (ix2 < n1) ? p + ix2 : p2 + (ix2 - n1);
        if (isStage) stageB(bj2, (tl + 1) & 1);
      }
    }

    // ---- compute tile ----
    const unsigned short* Bb = &S[(tl & 1) * 16384];
    f32x4 acc[2][4];
    #pragma unroll
    for (int fr = 0; fr < 2; ++fr)
      #pragma unroll
      for (int fc = 0; fc < 4; ++fc)
        acc[fr][fc] = (f32x4){0.f, 0.f, 0.f, 0.f};
    #pragma unroll
    for (int ks = 0; ks < 4; ++ks) {
      short8 bh[4];
      #pragma unroll
      for (int fc = 0; fc < 4; ++fc) {
        const int rb = wx * 64 + fc * 16 + mcol;
        const int pc = (ks * 4 + q) ^ mcol;
        bh[fc] = *(const short8*)&Bb[rb * 128 + pc * 8];
      }
      #pragma unroll
      for (int fc = 0; fc < 4; ++fc) {
        acc[0][fc] = __builtin_amdgcn_mfma_f32_16x16x32_bf16(Ah[0][ks], bh[fc], acc[0][fc], 0, 0, 0);
        acc[1][fc] = __builtin_amdgcn_mfma_f32_16x16x32_bf16(Ah[1][ks], bh[fc], acc[1][fc], 0, 0, 0);
        acc[0][fc] = __builtin_amdgcn_mfma_f32_16x16x32_bf16(Al[0][ks], bh[fc], acc[0][fc], 0, 0, 0);
        acc[1][fc] = __builtin_amdgcn_mfma_f32_16x16x32_bf16(Al[1][ks], bh[fc], acc[1][fc], 0, 0, 0);
      }
    }

    // ---- epilogue: negatives-only. C layout col = mcol, row = q*4 + rg ----
    float cN[4] = {0.f, 0.f, 0.f, 0.f};
#define EPILOGUE(DIAG_)                                                      \
    {                                                                        \
      _Pragma("unroll")                                                      \
      for (int fr = 0; fr < 2; ++fr) {                                       \
        _Pragma("unroll")                                                    \
        for (int rg = 0; rg < 4; ++rg) {                                     \
          float vn = 0.f;                                                    \
          _Pragma("unroll")                                                  \
          for (int fc = 0; fc < 4; ++fc) {                                   \
            const float s = acc[fr][fc][rg];                                 \
            const float u = fmaxf(fmaf(s, CE1, CE0), 0.f);                   \
            float e = fexp2(u * u);                                          \
            if (DIAG_) {                                                     \
              const int rl = wy * 32 + fr * 16 + q * 4 + rg;                 \
              const int cl = wx * 64 + fc * 16 + mcol;                       \
              e = (rl == cl) ? 0.f : e;                                      \
            }                                                                \
            vn += e;                                                         \
            cN[fc] += e;                                                     \
          }                                                                  \
          rowN[fr][rg] += vn;                                                \
        }                                                                    \
      }                                                                      \
    }
    if (bj == bi) EPILOGUE(true) else EPILOGUE(false)
#undef EPILOGUE

    // col partials: q-reduce then ds_write (16 lanes per wave)
    #pragma unroll
    for (int fc = 0; fc < 4; ++fc) {
      cN[fc] += __shfl_xor(cN[fc], 16);
      cN[fc] += __shfl_xor(cN[fc], 32);
    }
    if (q == 0) {
      #pragma unroll
      for (int fc = 0; fc < 4; ++fc)
        colbuf[tl & 1][wy][wx * 64 + fc * 16 + mcol] = cN[fc];
    }
    __builtin_amdgcn_s_waitcnt(49279);   // lgkm0: colbuf writes visible
    __builtin_amdgcn_s_barrier();

    // flush waves: combine 4 wy slices, fire-and-forget device atomics
    if (isFlush && bj != bi) {
      const int col = wx * 64 + lane;
      float sn = 0.f;
      #pragma unroll
      for (int w = 0; w < 4; ++w) sn += colbuf[tl & 1][w][col];
      atomicAdd(&gN[bj * 128 + col], sn);
    }
  }
  flushRows(cur_bi);
  // kernel end: dispatch completion drains all atomics — no counter, no
  // drain, no single-block finalize phase.
}

__global__ __launch_bounds__(1024) void finalize_kernel(
    const float* __restrict__ gP, const float* __restrict__ gN,
    float* __restrict__ out) {
  __shared__ float red[1024];
  const int tid = threadIdx.x;
  const float4* p4 = (const float4*)gP;
  const float4* n4 = (const float4*)gN;
  float local = 0.f;
  #pragma unroll
  for (int u = 0; u < 2; ++u) {
    const float4 p = p4[tid * 2 + u];
    const float4 n = n4[tid * 2 + u];
    local += log1pf(p.x * n.x) + log1pf(p.y * n.y) +
             log1pf(p.z * n.z) + log1pf(p.w * n.w);
  }
  red[tid] = local;
  __syncthreads();
  for (int s2 = 512; s2 > 0; s2 >>= 1) {
    if (tid < s2) red[tid] += red[tid + s2];
    __syncthreads();
  }
  if (tid == 0) out[0] = red[0] / (float)NR;
}

extern "C" void kernel_launch(void* const* d_in, const int* in_sizes, int n_in,
                              void* d_out, int out_size, void* d_ws, size_t ws_size,
                              hipStream_t stream) {
  const float* x  = (const float*)d_in[0];
  const int* tgt  = (const int*)d_in[1];
  float* out      = (float*)d_out;

  unsigned short* xhi = (unsigned short*)d_ws;
  unsigned short* xlo = xhi + (size_t)NR * DIMK;
  float* gP = (float*)((char*)d_ws + (size_t)NR * DIMK * 4);
  float* gN = gP + NR;

  normalize_split_kernel<<<NR / 4, 256, 0, stream>>>(x, xhi, xlo, gP, gN);
  simloss_kernel<<<NBLKS, 512, 0, stream>>>(xhi, xlo, tgt, gP, gN);
  finalize_kernel<<<1, 1024, 0, stream>>>(gP, gN, out);
}

// Round 6
// 111.887 us; speedup vs baseline: 1.1285x; 1.0471x over previous
//
#include <hip/hip_runtime.h>
#include <math.h>

// CircleLoss fused — R13b (resubmit; R13 bench was an infra container
// failure, no kernel verdict). Correction evicted from simloss into a
// parallel finalize kernel (512 blocks, block == class). R12 showed simloss
// busy-time doesn't close (18us busy vs 53.3 wall); the last serial phase at
// every block's head was the per-class correction (tgt scan + gram + ~500
// atomics before any MFMA). gP exists only from positives (class-local), and
// the e_n over-count is class-local too — so finalize computes P_i and
// Ncorr_i itself and emits log1p(P_i*(gN[i]-Ncorr_i)) per member row.
// simloss is now a pure negatives pipeline: stageA -> tile loop -> flush.
// Per-class partials combined via atomicExch + counter + atomic-read
// (R4-proven fence-free pattern), last block tree-sums 512 values.
// Main pipeline unchanged: upper-tri 128x128 tiles, pair scheduling, A panel
// in regs (2-term split bf16), B LDS-dbuf staged by stage waves,
// negatives-only epilogue, colbuf col combining.

#define NR    8192
#define DIMK  128
#define NT    64
#define NBLKS 512
#define NCLS  512
#define MAXC  96

// e_n(s) = exp(64*max(s-0.25,0)^2) = 2^(u*u), u = max(fma(s,CE1,CE0),0)
// CE1 = 8*sqrt(log2(e)), CE0 = -0.25*CE1
#define CE1 9.6089795f
#define CE0 -2.4022449f

typedef __attribute__((ext_vector_type(8))) short short8;
typedef __attribute__((ext_vector_type(4))) float f32x4;
typedef __attribute__((address_space(3))) uint32_t lds_u32;
typedef const __attribute__((address_space(1))) uint32_t glb_u32;

__device__ __forceinline__ unsigned short bf16_rne(float f) {
  uint32_t u = __float_as_uint(f);
  u += 0x7FFFu + ((u >> 16) & 1u);
  return (unsigned short)(u >> 16);
}

__device__ __forceinline__ float fexp2(float x) {
#if __has_builtin(__builtin_amdgcn_exp2f)
  return __builtin_amdgcn_exp2f(x);
#else
  return exp2f(x);
#endif
}

// ws: xhi bf16[NR*DIMK] (2MB) | xlo (2MB) | gN f32[NR] | gC f32[NCLS] | counter

__global__ __launch_bounds__(256) void normalize_split_kernel(
    const float* __restrict__ x, unsigned short* __restrict__ xhi,
    unsigned short* __restrict__ xlo, float* __restrict__ gN,
    int* __restrict__ counter) {
  if (blockIdx.x < 32) gN[blockIdx.x * 256 + threadIdx.x] = 0.f;
  if (blockIdx.x == 32 && threadIdx.x == 0) *counter = 0;

  const int wave = threadIdx.x >> 6;
  const int lane = threadIdx.x & 63;
  const int row  = blockIdx.x * 4 + wave;
  const float2 v = ((const float2*)(x + (size_t)row * DIMK))[lane];
  float ss = v.x * v.x + v.y * v.y;
  #pragma unroll
  for (int s = 1; s < 64; s <<= 1) ss += __shfl_xor(ss, s);
  const float r = rsqrtf(ss);
  const float a = v.x * r, b = v.y * r;
  const unsigned short ha = bf16_rne(a), hb = bf16_rne(b);
  const float haf = __uint_as_float((uint32_t)ha << 16);
  const float hbf = __uint_as_float((uint32_t)hb << 16);
  ushort2 hi, lo;
  hi.x = ha; hi.y = hb;
  lo.x = bf16_rne(a - haf); lo.y = bf16_rne(b - hbf);
  ((ushort2*)xhi)[(size_t)row * 64 + lane] = hi;
  ((ushort2*)xlo)[(size_t)row * 64 + lane] = lo;
}

__global__ __launch_bounds__(512, 2) void simloss_kernel(
    const unsigned short* __restrict__ xhi, const unsigned short* __restrict__ xlo,
    float* __restrict__ gN) {
  __shared__ unsigned short S[32768];   // 64KB: A stage, B dbuf
  __shared__ float colbuf[2][4][128];   // 4KB, double-buffered col partials (N only)

  const int tid  = threadIdx.x;
  const int wave = tid >> 6, lane = tid & 63;
  const int wy = wave & 3, wx = wave >> 2;   // frag grid: 4 row-waves x 2 col-waves
  const int q = lane >> 4, mcol = lane & 15;
  const bool isStage = (wy == 1) || (wy == 2);
  const bool isFlush = (wy == 0);
  const int srank = (wy - 1) + wx * 2;       // 0..3 for stage waves

  const int p  = blockIdx.x >> 4;            // pair index (0..31)
  const int b  = blockIdx.x & 15;
  const int n1 = NT - p;                     // tiles in panel1 (bi=p)
  const int t0 = (b * (NT + 1)) >> 4;        // 65 tiles per pair
  const int t1 = ((b + 1) * (NT + 1)) >> 4;
  const int ntile = t1 - t0;
  const int p2 = NT - 1 - p;                 // panel2 bi

  int cur_bi = (t0 < n1) ? p : p2;

  // ---- A staging (all waves). hi -> S[0..16K), lo -> S[16K..32K) ushorts ----
  auto stageA = [&](int bi) {
    const unsigned short* gh = xhi + (size_t)bi * 128 * DIMK;
    const unsigned short* gl = xlo + (size_t)bi * 128 * DIMK;
    #pragma unroll
    for (int g = 0; g < 4; ++g) {
      const int r  = wave * 16 + g * 4 + (lane >> 4);
      const int sc = (lane & 15) ^ (r & 15);   // XOR swizzle (R6-proven)
      __builtin_amdgcn_global_load_lds((glb_u32*)(gh + (size_t)r * DIMK + sc * 8),
          (lds_u32*)&S[(wave * 16 + g * 4) * 128], 16, 0, 0);
      __builtin_amdgcn_global_load_lds((glb_u32*)(gl + (size_t)r * DIMK + sc * 8),
          (lds_u32*)&S[16384 + (wave * 16 + g * 4) * 128], 16, 0, 0);
    }
  };
  // ---- B staging (stage waves only), 8 instrs each, 32KB tile ----
  auto stageB = [&](int bj, int buf) {
    const unsigned short* gb = xhi + (size_t)bj * 128 * DIMK;
    unsigned short* dst = &S[buf * 16384];
    #pragma unroll
    for (int g = 0; g < 8; ++g) {
      const int r  = srank * 32 + g * 4 + (lane >> 4);
      const int sc = (lane & 15) ^ (r & 15);
      __builtin_amdgcn_global_load_lds((glb_u32*)(gb + (size_t)r * DIMK + sc * 8),
          (lds_u32*)&dst[(srank * 32 + g * 4) * 128], 16, 0, 0);
    }
  };

  short8 Ah[2][4], Al[2][4];
  auto extractA = [&]() {
    #pragma unroll
    for (int fr = 0; fr < 2; ++fr) {
      const int r = wy * 32 + fr * 16 + mcol;
      #pragma unroll
      for (int ks = 0; ks < 4; ++ks) {
        const int pc = (ks * 4 + q) ^ mcol;
        Ah[fr][ks] = *(const short8*)&S[r * 128 + pc * 8];
        Al[fr][ks] = *(const short8*)&S[16384 + r * 128 + pc * 8];
      }
    }
  };

  float rowN[2][4] = {{0.f}};
  auto flushRows = [&](int bi_) {
    #pragma unroll
    for (int fr = 0; fr < 2; ++fr)
      #pragma unroll
      for (int rg = 0; rg < 4; ++rg) {
        float vn = rowN[fr][rg];
        #pragma unroll
        for (int m2 = 1; m2 < 16; m2 <<= 1) vn += __shfl_xor(vn, m2);
        if (mcol == 0)
          atomicAdd(&gN[bi_ * 128 + wy * 32 + fr * 16 + q * 4 + rg], vn);
      }
  };

  stageA(cur_bi);
  __syncthreads();            // A staged
  extractA();
  __builtin_amdgcn_s_waitcnt(49279);   // lgkm0: all frag reads done
  __builtin_amdgcn_s_barrier();        // -> S reusable as B buffers
  if (isStage) stageB((t0 < n1) ? p + t0 : p2 + (t0 - n1), 0);

  for (int tl = 0; tl < ntile; ++tl) {
    const int ix = t0 + tl;
    const int bi = (ix < n1) ? p : p2;
    const int bj = (ix < n1) ? p + ix : p2 + (ix - n1);

    if (bi != cur_bi) {       // panel switch (at most once per block)
      flushRows(cur_bi);
      cur_bi = bi;
      stageA(cur_bi);         // overwrites both B buffers (none pending)
      __syncthreads();
      extractA();
      #pragma unroll
      for (int fr = 0; fr < 2; ++fr)
        #pragma unroll
        for (int rg = 0; rg < 4; ++rg) rowN[fr][rg] = 0.f;
      __builtin_amdgcn_s_waitcnt(49279);
      __builtin_amdgcn_s_barrier();
      if (isStage) stageB(bj, tl & 1);
    }

    // start barrier: only stage waves drain their B loads (vm0+lgkm0 = 112)
    if (isStage) __builtin_amdgcn_s_waitcnt(112);
    __builtin_amdgcn_s_barrier();

    // prefetch next tile's B (same panel only; cross-panel handled above)
    if (tl + 1 < ntile) {
      const int ix2 = ix + 1;
      if ((ix2 < n1) == (ix < n1)) {
        const int bj2 = (ix2 < n1) ? p + ix2 : p2 + (ix2 - n1);
        if (isStage) stageB(bj2, (tl + 1) & 1);
      }
    }

    // ---- compute tile ----
    const unsigned short* Bb = &S[(tl & 1) * 16384];
    f32x4 acc[2][4];
    #pragma unroll
    for (int fr = 0; fr < 2; ++fr)
      #pragma unroll
      for (int fc = 0; fc < 4; ++fc)
        acc[fr][fc] = (f32x4){0.f, 0.f, 0.f, 0.f};
    #pragma unroll
    for (int ks = 0; ks < 4; ++ks) {
      short8 bh[4];
      #pragma unroll
      for (int fc = 0; fc < 4; ++fc) {
        const int rb = wx * 64 + fc * 16 + mcol;
        const int pc = (ks * 4 + q) ^ mcol;
        bh[fc] = *(const short8*)&Bb[rb * 128 + pc * 8];
      }
      #pragma unroll
      for (int fc = 0; fc < 4; ++fc) {
        acc[0][fc] = __builtin_amdgcn_mfma_f32_16x16x32_bf16(Ah[0][ks], bh[fc], acc[0][fc], 0, 0, 0);
        acc[1][fc] = __builtin_amdgcn_mfma_f32_16x16x32_bf16(Ah[1][ks], bh[fc], acc[1][fc], 0, 0, 0);
        acc[0][fc] = __builtin_amdgcn_mfma_f32_16x16x32_bf16(Al[0][ks], bh[fc], acc[0][fc], 0, 0, 0);
        acc[1][fc] = __builtin_amdgcn_mfma_f32_16x16x32_bf16(Al[1][ks], bh[fc], acc[1][fc], 0, 0, 0);
      }
    }

    // ---- epilogue: negatives-only. C layout col = mcol, row = q*4 + rg ----
    float cN[4] = {0.f, 0.f, 0.f, 0.f};
#define EPILOGUE(DIAG_)                                                      \
    {                                                                        \
      _Pragma("unroll")                                                      \
      for (int fr = 0; fr < 2; ++fr) {                                       \
        _Pragma("unroll")                                                    \
        for (int rg = 0; rg < 4; ++rg) {                                     \
          float vn = 0.f;                                                    \
          _Pragma("unroll")                                                  \
          for (int fc = 0; fc < 4; ++fc) {                                   \
            const float s = acc[fr][fc][rg];                                 \
            const float u = fmaxf(fmaf(s, CE1, CE0), 0.f);                   \
            float e = fexp2(u * u);                                          \
            if (DIAG_) {                                                     \
              const int rl = wy * 32 + fr * 16 + q * 4 + rg;                 \
              const int cl = wx * 64 + fc * 16 + mcol;                       \
              e = (rl == cl) ? 0.f : e;                                      \
            }                                                                \
            vn += e;                                                         \
            cN[fc] += e;                                                     \
          }                                                                  \
          rowN[fr][rg] += vn;                                                \
        }                                                                    \
      }                                                                      \
    }
    if (bj == bi) EPILOGUE(true) else EPILOGUE(false)
#undef EPILOGUE

    // col partials: q-reduce then ds_write (16 lanes per wave)
    #pragma unroll
    for (int fc = 0; fc < 4; ++fc) {
      cN[fc] += __shfl_xor(cN[fc], 16);
      cN[fc] += __shfl_xor(cN[fc], 32);
    }
    if (q == 0) {
      #pragma unroll
      for (int fc = 0; fc < 4; ++fc)
        colbuf[tl & 1][wy][wx * 64 + fc * 16 + mcol] = cN[fc];
    }
    __builtin_amdgcn_s_waitcnt(49279);   // lgkm0: colbuf writes visible
    __builtin_amdgcn_s_barrier();

    // flush waves: combine 4 wy slices, fire-and-forget device atomics
    if (isFlush && bj != bi) {
      const int col = wx * 64 + lane;
      float sn = 0.f;
      #pragma unroll
      for (int w = 0; w < 4; ++w) sn += colbuf[tl & 1][w][col];
      atomicAdd(&gN[bj * 128 + col], sn);
    }
  }
  flushRows(cur_bi);
  // kernel end: dispatch completion drains all atomics.
}

// ---- finalize: 512 blocks, block == class. Computes P_i (all positives
// live within a class), the e_n over-count correction, and the per-member
// log1p terms; per-class partials combined fence-free (R4 pattern). ----
__global__ __launch_bounds__(256) void finalize_kernel(
    const unsigned short* __restrict__ xhi, const unsigned short* __restrict__ xlo,
    const int* __restrict__ tgt, const float* __restrict__ gN,
    float* __restrict__ gC, int* __restrict__ counter, float* __restrict__ out) {
  __shared__ float Sf[MAXC * 129];   // ~48KB member vectors, stride-129
  __shared__ float Pv[MAXC];
  __shared__ float Ncor[MAXC];
  __shared__ int midx[MAXC];
  __shared__ float red[256];
  __shared__ int scnt;
  __shared__ int islast;

  const int tid = threadIdx.x;
  const int me  = (int)blockIdx.x;

  if (tid == 0) scnt = 0;
  if (tid < MAXC) { Pv[tid] = 0.f; Ncor[tid] = 0.f; }
  __syncthreads();

  // scan tgt (32KB, L2-resident) for members of this class
  const int4* t4 = (const int4*)tgt;
  for (int v = tid; v < NR / 4; v += 256) {   // 8 iterations
    const int4 tv = t4[v];
    const int base = v * 4;
    if (tv.x == me) { const int s_ = atomicAdd(&scnt, 1); if (s_ < MAXC) midx[s_] = base; }
    if (tv.y == me) { const int s_ = atomicAdd(&scnt, 1); if (s_ < MAXC) midx[s_] = base + 1; }
    if (tv.z == me) { const int s_ = atomicAdd(&scnt, 1); if (s_ < MAXC) midx[s_] = base + 2; }
    if (tv.w == me) { const int s_ = atomicAdd(&scnt, 1); if (s_ < MAXC) midx[s_] = base + 3; }
  }
  __syncthreads();
  const int m = (scnt < MAXC) ? scnt : MAXC;

  // load member vectors (hi+lo reconstructed f32)
  for (int v = tid; v < m * 32; v += 256) {
    const int r = v >> 5, c4 = v & 31;
    const int row = midx[r];
    const ushort4 h = ((const ushort4*)(xhi + (size_t)row * DIMK))[c4];
    const ushort4 l = ((const ushort4*)(xlo + (size_t)row * DIMK))[c4];
    float* d = &Sf[r * 129 + c4 * 4];
    d[0] = __uint_as_float((uint32_t)h.x << 16) + __uint_as_float((uint32_t)l.x << 16);
    d[1] = __uint_as_float((uint32_t)h.y << 16) + __uint_as_float((uint32_t)l.y << 16);
    d[2] = __uint_as_float((uint32_t)h.z << 16) + __uint_as_float((uint32_t)l.z << 16);
    d[3] = __uint_as_float((uint32_t)h.w << 16) + __uint_as_float((uint32_t)l.w << 16);
  }
  __syncthreads();

  // class gram: P_i += ep(s_ij) (j incl. diag, matching ref mask);
  // Ncor_i += en(s_ij) for j != i (the main loop's same-class over-count)
  for (int pr = tid; pr < m * m; pr += 256) {
    const int i = pr / m, j = pr - i * m;
    const float* vi = &Sf[i * 129];
    const float* vj = &Sf[j * 129];
    float s = 0.f;
    #pragma unroll 8
    for (int d = 0; d < 128; ++d) s = fmaf(vi[d], vj[d], s);
    const float ep = __expf(fmaxf(1.25f - s, 0.f) * fmaf(s, 64.f, -48.f));
    atomicAdd(&Pv[i], ep);
    if (i != j) {
      const float u = fmaxf(fmaf(s, CE1, CE0), 0.f);
      atomicAdd(&Ncor[i], fexp2(u * u));
    }
  }
  __syncthreads();

  // per-member loss terms
  float local = 0.f;
  for (int r = tid; r < m; r += 256) {
    const int gi = midx[r];
    local += log1pf(Pv[r] * (gN[gi] - Ncor[r]));
  }
  red[tid] = local;
  __syncthreads();
  #pragma unroll
  for (int s2 = 128; s2 > 0; s2 >>= 1) {
    if (tid < s2) red[tid] += red[tid + s2];
    __syncthreads();
  }
  if (tid == 0) atomicExch(&gC[me], red[0]);   // memory-side, no init needed

  // fence-free rendezvous (R4-proven)
  __builtin_amdgcn_s_waitcnt(0);
  __syncthreads();
  if (tid == 0) islast = (atomicAdd(counter, 1) == NCLS - 1) ? 1 : 0;
  __syncthreads();
  if (islast) {
    float sum = 0.f;
    #pragma unroll
    for (int u = 0; u < 2; ++u)
      sum += atomicAdd(&gC[tid * 2 + u], 0.0f);   // atomic read (cache-bypass)
    red[tid] = sum;
    __syncthreads();
    #pragma unroll
    for (int s2 = 128; s2 > 0; s2 >>= 1) {
      if (tid < s2) red[tid] += red[tid + s2];
      __syncthreads();
    }
    if (tid == 0) out[0] = red[0] / (float)NR;
  }
}

extern "C" void kernel_launch(void* const* d_in, const int* in_sizes, int n_in,
                              void* d_out, int out_size, void* d_ws, size_t ws_size,
                              hipStream_t stream) {
  const float* x  = (const float*)d_in[0];
  const int* tgt  = (const int*)d_in[1];
  float* out      = (float*)d_out;

  unsigned short* xhi = (unsigned short*)d_ws;
  unsigned short* xlo = xhi + (size_t)NR * DIMK;
  float* gN = (float*)((char*)d_ws + (size_t)NR * DIMK * 4);
  float* gC = gN + NR;
  int* counter = (int*)(gC + NCLS);

  normalize_split_kernel<<<NR / 4, 256, 0, stream>>>(x, xhi, xlo, gN, counter);
  simloss_kernel<<<NBLKS, 512, 0, stream>>>(xhi, xlo, gN);
  finalize_kernel<<<NCLS, 256, 0, stream>>>(xhi, xlo, tgt, gN, gC, counter, out);
}

// Round 7
// 111.339 us; speedup vs baseline: 1.1341x; 1.0049x over previous
//
#include <hip/hip_runtime.h>
#include <math.h>

// CircleLoss fused — R14: R13b + two cuts in the controllable region
// (profile showed a fixed ~43us 256MiB harness workspace-poison fill in the
// timed path; simloss now < 42.6us, hidden below it).
//  (1) normalize vectorized: float4 loads (16B/lane), 32 lanes/row,
//      2 rows/wave, ushort4 stores, 1024 blocks (was float2/8B, 2048 blocks;
//      ~5x off its 1.3us roofline).
//  (2) simloss: colbuf flush DEFERRED one tile -> second per-tile barrier
//      removed. Flush waves combine colbuf[(tl-1)&1] right after the start
//      barrier, overlapped with ds_read/MFMA of the current tile. The
//      per-wave lgkm0 drain before the start barrier (stage: vm0+lgkm0)
//      orders the previous tile's colbuf ds_writes AND guarantees B-dbuf
//      read-before-overwrite, so no extra sync is needed.
// Rest unchanged from R13b: pure-negatives MFMA pipeline (upper-tri 128x128
// tiles, pair scheduling, A panel in regs, 2-term split bf16, B LDS-dbuf by
// stage waves, XOR swizzle), per-class positive correction + log1p in a
// 512-block finalize kernel with the R4 fence-free rendezvous.

#define NR    8192
#define DIMK  128
#define NT    64
#define NBLKS 512
#define NCLS  512
#define MAXC  96

// e_n(s) = exp(64*max(s-0.25,0)^2) = 2^(u*u), u = max(fma(s,CE1,CE0),0)
// CE1 = 8*sqrt(log2(e)), CE0 = -0.25*CE1
#define CE1 9.6089795f
#define CE0 -2.4022449f

typedef __attribute__((ext_vector_type(8))) short short8;
typedef __attribute__((ext_vector_type(4))) float f32x4;
typedef __attribute__((address_space(3))) uint32_t lds_u32;
typedef const __attribute__((address_space(1))) uint32_t glb_u32;

__device__ __forceinline__ unsigned short bf16_rne(float f) {
  uint32_t u = __float_as_uint(f);
  u += 0x7FFFu + ((u >> 16) & 1u);
  return (unsigned short)(u >> 16);
}

__device__ __forceinline__ float fexp2(float x) {
#if __has_builtin(__builtin_amdgcn_exp2f)
  return __builtin_amdgcn_exp2f(x);
#else
  return exp2f(x);
#endif
}

// ws: xhi bf16[NR*DIMK] (2MB) | xlo (2MB) | gN f32[NR] | gC f32[NCLS] | counter

__global__ __launch_bounds__(256) void normalize_split_kernel(
    const float* __restrict__ x, unsigned short* __restrict__ xhi,
    unsigned short* __restrict__ xlo, float* __restrict__ gN,
    int* __restrict__ counter) {
  if (blockIdx.x < 32) gN[blockIdx.x * 256 + threadIdx.x] = 0.f;
  if (blockIdx.x == 32 && threadIdx.x == 0) *counter = 0;

  const int wave = threadIdx.x >> 6;
  const int lane = threadIdx.x & 63;
  const int l32  = lane & 31;                      // 32 lanes per row
  const int row  = blockIdx.x * 8 + wave * 2 + (lane >> 5);
  const float4 v = ((const float4*)(x + (size_t)row * DIMK))[l32];
  float ss = v.x * v.x + v.y * v.y + v.z * v.z + v.w * v.w;
  #pragma unroll
  for (int s = 1; s < 32; s <<= 1) ss += __shfl_xor(ss, s);  // stays in-half
  const float r = rsqrtf(ss);
  const float a0 = v.x * r, a1 = v.y * r, a2 = v.z * r, a3 = v.w * r;
  ushort4 hi, lo;
  hi.x = bf16_rne(a0); hi.y = bf16_rne(a1);
  hi.z = bf16_rne(a2); hi.w = bf16_rne(a3);
  lo.x = bf16_rne(a0 - __uint_as_float((uint32_t)hi.x << 16));
  lo.y = bf16_rne(a1 - __uint_as_float((uint32_t)hi.y << 16));
  lo.z = bf16_rne(a2 - __uint_as_float((uint32_t)hi.z << 16));
  lo.w = bf16_rne(a3 - __uint_as_float((uint32_t)hi.w << 16));
  ((ushort4*)xhi)[(size_t)row * 32 + l32] = hi;
  ((ushort4*)xlo)[(size_t)row * 32 + l32] = lo;
}

__global__ __launch_bounds__(512, 2) void simloss_kernel(
    const unsigned short* __restrict__ xhi, const unsigned short* __restrict__ xlo,
    float* __restrict__ gN) {
  __shared__ unsigned short S[32768];   // 64KB: A stage, B dbuf
  __shared__ float colbuf[2][4][128];   // 4KB, double-buffered col partials (N only)

  const int tid  = threadIdx.x;
  const int wave = tid >> 6, lane = tid & 63;
  const int wy = wave & 3, wx = wave >> 2;   // frag grid: 4 row-waves x 2 col-waves
  const int q = lane >> 4, mcol = lane & 15;
  const bool isStage = (wy == 1) || (wy == 2);
  const bool isFlush = (wy == 0);
  const int srank = (wy - 1) + wx * 2;       // 0..3 for stage waves

  const int p  = blockIdx.x >> 4;            // pair index (0..31)
  const int b  = blockIdx.x & 15;
  const int n1 = NT - p;                     // tiles in panel1 (bi=p)
  const int t0 = (b * (NT + 1)) >> 4;        // 65 tiles per pair
  const int t1 = ((b + 1) * (NT + 1)) >> 4;
  const int ntile = t1 - t0;
  const int p2 = NT - 1 - p;                 // panel2 bi

  int cur_bi = (t0 < n1) ? p : p2;

  // ---- A staging (all waves). hi -> S[0..16K), lo -> S[16K..32K) ushorts ----
  auto stageA = [&](int bi) {
    const unsigned short* gh = xhi + (size_t)bi * 128 * DIMK;
    const unsigned short* gl = xlo + (size_t)bi * 128 * DIMK;
    #pragma unroll
    for (int g = 0; g < 4; ++g) {
      const int r  = wave * 16 + g * 4 + (lane >> 4);
      const int sc = (lane & 15) ^ (r & 15);   // XOR swizzle (R6-proven)
      __builtin_amdgcn_global_load_lds((glb_u32*)(gh + (size_t)r * DIMK + sc * 8),
          (lds_u32*)&S[(wave * 16 + g * 4) * 128], 16, 0, 0);
      __builtin_amdgcn_global_load_lds((glb_u32*)(gl + (size_t)r * DIMK + sc * 8),
          (lds_u32*)&S[16384 + (wave * 16 + g * 4) * 128], 16, 0, 0);
    }
  };
  // ---- B staging (stage waves only), 8 instrs each, 32KB tile ----
  auto stageB = [&](int bj, int buf) {
    const unsigned short* gb = xhi + (size_t)bj * 128 * DIMK;
    unsigned short* dst = &S[buf * 16384];
    #pragma unroll
    for (int g = 0; g < 8; ++g) {
      const int r  = srank * 32 + g * 4 + (lane >> 4);
      const int sc = (lane & 15) ^ (r & 15);
      __builtin_amdgcn_global_load_lds((glb_u32*)(gb + (size_t)r * DIMK + sc * 8),
          (lds_u32*)&dst[(srank * 32 + g * 4) * 128], 16, 0, 0);
    }
  };

  short8 Ah[2][4], Al[2][4];
  auto extractA = [&]() {
    #pragma unroll
    for (int fr = 0; fr < 2; ++fr) {
      const int r = wy * 32 + fr * 16 + mcol;
      #pragma unroll
      for (int ks = 0; ks < 4; ++ks) {
        const int pc = (ks * 4 + q) ^ mcol;
        Ah[fr][ks] = *(const short8*)&S[r * 128 + pc * 8];
        Al[fr][ks] = *(const short8*)&S[16384 + r * 128 + pc * 8];
      }
    }
  };

  float rowN[2][4] = {{0.f}};
  auto flushRows = [&](int bi_) {
    #pragma unroll
    for (int fr = 0; fr < 2; ++fr)
      #pragma unroll
      for (int rg = 0; rg < 4; ++rg) {
        float vn = rowN[fr][rg];
        #pragma unroll
        for (int m2 = 1; m2 < 16; m2 <<= 1) vn += __shfl_xor(vn, m2);
        if (mcol == 0)
          atomicAdd(&gN[bi_ * 128 + wy * 32 + fr * 16 + q * 4 + rg], vn);
      }
  };

  stageA(cur_bi);
  __syncthreads();            // A staged
  extractA();
  __builtin_amdgcn_s_waitcnt(49279);   // lgkm0: all frag reads done
  __builtin_amdgcn_s_barrier();        // -> S reusable as B buffers
  if (isStage) stageB((t0 < n1) ? p + t0 : p2 + (t0 - n1), 0);

  int pbi = -1, pbj = -1;              // previous tile (deferred col flush)

  for (int tl = 0; tl < ntile; ++tl) {
    const int ix = t0 + tl;
    const int bi = (ix < n1) ? p : p2;
    const int bj = (ix < n1) ? p + ix : p2 + (ix - n1);

    if (bi != cur_bi) {       // panel switch (at most once per block)
      flushRows(cur_bi);
      cur_bi = bi;
      stageA(cur_bi);         // overwrites both B buffers (none pending)
      __syncthreads();
      extractA();
      #pragma unroll
      for (int fr = 0; fr < 2; ++fr)
        #pragma unroll
        for (int rg = 0; rg < 4; ++rg) rowN[fr][rg] = 0.f;
      __builtin_amdgcn_s_waitcnt(49279);
      __builtin_amdgcn_s_barrier();
      if (isStage) stageB(bj, tl & 1);
    }

    // start barrier: stage waves drain their B loads (vm0+lgkm0 = 112);
    // all other waves drain lgkm0 so last tile's colbuf writes are visible
    // and last tile's B ds_reads are provably complete (dbuf safety).
    if (isStage) __builtin_amdgcn_s_waitcnt(112);
    else         __builtin_amdgcn_s_waitcnt(49279);
    __builtin_amdgcn_s_barrier();

    // deferred col flush of PREVIOUS tile (overlaps this tile's compute)
    if (isFlush && pbj >= 0 && pbj != pbi) {
      const int col = wx * 64 + lane;
      float sn = 0.f;
      #pragma unroll
      for (int w = 0; w < 4; ++w) sn += colbuf[(tl & 1) ^ 1][w][col];
      atomicAdd(&gN[pbj * 128 + col], sn);
    }

    // prefetch next tile's B (same panel only; cross-panel handled above)
    if (tl + 1 < ntile) {
      const int ix2 = ix + 1;
      if ((ix2 < n1) == (ix < n1)) {
        const int bj2 = (ix2 < n1) ? p + ix2 : p2 + (ix2 - n1);
        if (isStage) stageB(bj2, (tl + 1) & 1);
      }
    }

    // ---- compute tile ----
    const unsigned short* Bb = &S[(tl & 1) * 16384];
    f32x4 acc[2][4];
    #pragma unroll
    for (int fr = 0; fr < 2; ++fr)
      #pragma unroll
      for (int fc = 0; fc < 4; ++fc)
        acc[fr][fc] = (f32x4){0.f, 0.f, 0.f, 0.f};
    #pragma unroll
    for (int ks = 0; ks < 4; ++ks) {
      short8 bh[4];
      #pragma unroll
      for (int fc = 0; fc < 4; ++fc) {
        const int rb = wx * 64 + fc * 16 + mcol;
        const int pc = (ks * 4 + q) ^ mcol;
        bh[fc] = *(const short8*)&Bb[rb * 128 + pc * 8];
      }
      #pragma unroll
      for (int fc = 0; fc < 4; ++fc) {
        acc[0][fc] = __builtin_amdgcn_mfma_f32_16x16x32_bf16(Ah[0][ks], bh[fc], acc[0][fc], 0, 0, 0);
        acc[1][fc] = __builtin_amdgcn_mfma_f32_16x16x32_bf16(Ah[1][ks], bh[fc], acc[1][fc], 0, 0, 0);
        acc[0][fc] = __builtin_amdgcn_mfma_f32_16x16x32_bf16(Al[0][ks], bh[fc], acc[0][fc], 0, 0, 0);
        acc[1][fc] = __builtin_amdgcn_mfma_f32_16x16x32_bf16(Al[1][ks], bh[fc], acc[1][fc], 0, 0, 0);
      }
    }

    // ---- epilogue: negatives-only. C layout col = mcol, row = q*4 + rg ----
    float cN[4] = {0.f, 0.f, 0.f, 0.f};
#define EPILOGUE(DIAG_)                                                      \
    {                                                                        \
      _Pragma("unroll")                                                      \
      for (int fr = 0; fr < 2; ++fr) {                                       \
        _Pragma("unroll")                                                    \
        for (int rg = 0; rg < 4; ++rg) {                                     \
          float vn = 0.f;                                                    \
          _Pragma("unroll")                                                  \
          for (int fc = 0; fc < 4; ++fc) {                                   \
            const float s = acc[fr][fc][rg];                                 \
            const float u = fmaxf(fmaf(s, CE1, CE0), 0.f);                   \
            float e = fexp2(u * u);                                          \
            if (DIAG_) {                                                     \
              const int rl = wy * 32 + fr * 16 + q * 4 + rg;                 \
              const int cl = wx * 64 + fc * 16 + mcol;                       \
              e = (rl == cl) ? 0.f : e;                                      \
            }                                                                \
            vn += e;                                                         \
            cN[fc] += e;                                                     \
          }                                                                  \
          rowN[fr][rg] += vn;                                                \
        }                                                                    \
      }                                                                      \
    }
    if (bj == bi) EPILOGUE(true) else EPILOGUE(false)
#undef EPILOGUE

    // col partials: q-reduce then ds_write (16 lanes per wave); flushed at
    // the NEXT tile's start barrier (deferred) — no barrier here.
    #pragma unroll
    for (int fc = 0; fc < 4; ++fc) {
      cN[fc] += __shfl_xor(cN[fc], 16);
      cN[fc] += __shfl_xor(cN[fc], 32);
    }
    if (q == 0) {
      #pragma unroll
      for (int fc = 0; fc < 4; ++fc)
        colbuf[tl & 1][wy][wx * 64 + fc * 16 + mcol] = cN[fc];
    }

    pbi = bi; pbj = bj;
  }

  // tail: flush the last tile's colbuf, then row sums
  __builtin_amdgcn_s_waitcnt(49279);
  __builtin_amdgcn_s_barrier();
  if (isFlush && pbj >= 0 && pbj != pbi) {
    const int col = wx * 64 + lane;
    float sn = 0.f;
    #pragma unroll
    for (int w = 0; w < 4; ++w) sn += colbuf[(ntile - 1) & 1][w][col];
    atomicAdd(&gN[pbj * 128 + col], sn);
  }
  flushRows(cur_bi);
  // kernel end: dispatch completion drains all atomics.
}

// ---- finalize: 512 blocks, block == class. Computes P_i (all positives
// live within a class), the e_n over-count correction, and the per-member
// log1p terms; per-class partials combined fence-free (R4 pattern). ----
__global__ __launch_bounds__(256) void finalize_kernel(
    const unsigned short* __restrict__ xhi, const unsigned short* __restrict__ xlo,
    const int* __restrict__ tgt, const float* __restrict__ gN,
    float* __restrict__ gC, int* __restrict__ counter, float* __restrict__ out) {
  __shared__ float Sf[MAXC * 129];   // ~48KB member vectors, stride-129
  __shared__ float Pv[MAXC];
  __shared__ float Ncor[MAXC];
  __shared__ int midx[MAXC];
  __shared__ float red[256];
  __shared__ int scnt;
  __shared__ int islast;

  const int tid = threadIdx.x;
  const int me  = (int)blockIdx.x;

  if (tid == 0) scnt = 0;
  if (tid < MAXC) { Pv[tid] = 0.f; Ncor[tid] = 0.f; }
  __syncthreads();

  // scan tgt (32KB, L2-resident) for members of this class
  const int4* t4 = (const int4*)tgt;
  for (int v = tid; v < NR / 4; v += 256) {   // 8 iterations
    const int4 tv = t4[v];
    const int base = v * 4;
    if (tv.x == me) { const int s_ = atomicAdd(&scnt, 1); if (s_ < MAXC) midx[s_] = base; }
    if (tv.y == me) { const int s_ = atomicAdd(&scnt, 1); if (s_ < MAXC) midx[s_] = base + 1; }
    if (tv.z == me) { const int s_ = atomicAdd(&scnt, 1); if (s_ < MAXC) midx[s_] = base + 2; }
    if (tv.w == me) { const int s_ = atomicAdd(&scnt, 1); if (s_ < MAXC) midx[s_] = base + 3; }
  }
  __syncthreads();
  const int m = (scnt < MAXC) ? scnt : MAXC;

  // load member vectors (hi+lo reconstructed f32)
  for (int v = tid; v < m * 32; v += 256) {
    const int r = v >> 5, c4 = v & 31;
    const int row = midx[r];
    const ushort4 h = ((const ushort4*)(xhi + (size_t)row * DIMK))[c4];
    const ushort4 l = ((const ushort4*)(xlo + (size_t)row * DIMK))[c4];
    float* d = &Sf[r * 129 + c4 * 4];
    d[0] = __uint_as_float((uint32_t)h.x << 16) + __uint_as_float((uint32_t)l.x << 16);
    d[1] = __uint_as_float((uint32_t)h.y << 16) + __uint_as_float((uint32_t)l.y << 16);
    d[2] = __uint_as_float((uint32_t)h.z << 16) + __uint_as_float((uint32_t)l.z << 16);
    d[3] = __uint_as_float((uint32_t)h.w << 16) + __uint_as_float((uint32_t)l.w << 16);
  }
  __syncthreads();

  // class gram: P_i += ep(s_ij) (j incl. diag, matching ref mask);
  // Ncor_i += en(s_ij) for j != i (the main loop's same-class over-count)
  for (int pr = tid; pr < m * m; pr += 256) {
    const int i = pr / m, j = pr - i * m;
    const float* vi = &Sf[i * 129];
    const float* vj = &Sf[j * 129];
    float s = 0.f;
    #pragma unroll 8
    for (int d = 0; d < 128; ++d) s = fmaf(vi[d], vj[d], s);
    const float ep = __expf(fmaxf(1.25f - s, 0.f) * fmaf(s, 64.f, -48.f));
    atomicAdd(&Pv[i], ep);
    if (i != j) {
      const float u = fmaxf(fmaf(s, CE1, CE0), 0.f);
      atomicAdd(&Ncor[i], fexp2(u * u));
    }
  }
  __syncthreads();

  // per-member loss terms
  float local = 0.f;
  for (int r = tid; r < m; r += 256) {
    const int gi = midx[r];
    local += log1pf(Pv[r] * (gN[gi] - Ncor[r]));
  }
  red[tid] = local;
  __syncthreads();
  #pragma unroll
  for (int s2 = 128; s2 > 0; s2 >>= 1) {
    if (tid < s2) red[tid] += red[tid + s2];
    __syncthreads();
  }
  if (tid == 0) atomicExch(&gC[me], red[0]);   // memory-side, no init needed

  // fence-free rendezvous (R4-proven)
  __builtin_amdgcn_s_waitcnt(0);
  __syncthreads();
  if (tid == 0) islast = (atomicAdd(counter, 1) == NCLS - 1) ? 1 : 0;
  __syncthreads();
  if (islast) {
    float sum = 0.f;
    #pragma unroll
    for (int u = 0; u < 2; ++u)
      sum += atomicAdd(&gC[tid * 2 + u], 0.0f);   // atomic read (cache-bypass)
    red[tid] = sum;
    __syncthreads();
    #pragma unroll
    for (int s2 = 128; s2 > 0; s2 >>= 1) {
      if (tid < s2) red[tid] += red[tid + s2];
      __syncthreads();
    }
    if (tid == 0) out[0] = red[0] / (float)NR;
  }
}

extern "C" void kernel_launch(void* const* d_in, const int* in_sizes, int n_in,
                              void* d_out, int out_size, void* d_ws, size_t ws_size,
                              hipStream_t stream) {
  const float* x  = (const float*)d_in[0];
  const int* tgt  = (const int*)d_in[1];
  float* out      = (float*)d_out;

  unsigned short* xhi = (unsigned short*)d_ws;
  unsigned short* xlo = xhi + (size_t)NR * DIMK;
  float* gN = (float*)((char*)d_ws + (size_t)NR * DIMK * 4);
  float* gC = gN + NR;
  int* counter = (int*)(gC + NCLS);

  normalize_split_kernel<<<NR / 8, 256, 0, stream>>>(x, xhi, xlo, gN, counter);
  simloss_kernel<<<NBLKS, 512, 0, stream>>>(xhi, xlo, gN);
  finalize_kernel<<<NCLS, 256, 0, stream>>>(xhi, xlo, tgt, gN, gC, counter, out);
}

// Round 9
// 110.227 us; speedup vs baseline: 1.1455x; 1.0101x over previous
//
#include <hip/hip_runtime.h>
#include <math.h>

// CircleLoss fused — R16 = R15 with the Row write-conflict fixed. R15's
// atomic->store conversion dropped half of every direct row sum: flushRows'
// slot Row[b][row] was written by BOTH wx waves (each holding one 64-col
// half of the row sum; atomicAdd used to combine them). Fix: Row widened to
// 32 slices, slot (b*2+wx) — every wave owns a unique slice; finalize sums
// 64 Col + 32 Row slots per member row.
// Rationale (R15): wave-seconds analysis (Occ% x dur ~ 9.5us conserved
// R11-R12) shows waves resident only ~19us of simloss's ~41-53us window;
// the rest is the end-of-dispatch drain retiring ~100-200k fire-and-forget
// device atomics RMW-serializing on gN's 512 cache lines. Zero atomics in
// simloss -> plain stores to unique scratch slots; finalize (512 blocks =
// classes) reduces them on the fly. gN never materialized.

#define NR    8192
#define DIMK  128
#define NT    64
#define NBLKS 512
#define NCLS  512
#define MAXC  96

// e_n(s) = exp(64*max(s-0.25,0)^2) = 2^(u*u), u = max(fma(s,CE1,CE0),0)
#define CE1 9.6089795f
#define CE0 -2.4022449f

typedef __attribute__((ext_vector_type(8))) short short8;
typedef __attribute__((ext_vector_type(4))) float f32x4;
typedef __attribute__((address_space(3))) uint32_t lds_u32;
typedef const __attribute__((address_space(1))) uint32_t glb_u32;

__device__ __forceinline__ unsigned short bf16_rne(float f) {
  uint32_t u = __float_as_uint(f);
  u += 0x7FFFu + ((u >> 16) & 1u);
  return (unsigned short)(u >> 16);
}

__device__ __forceinline__ float fexp2(float x) {
#if __has_builtin(__builtin_amdgcn_exp2f)
  return __builtin_amdgcn_exp2f(x);
#else
  return exp2f(x);
#endif
}

// ws: xhi bf16[NR*DIMK] 2MB | xlo 2MB | Col f32[64*NR] 2MB |
//     Row f32[32*NR] 1MB | gC f32[NCLS] | counter

__global__ __launch_bounds__(256) void normalize_split_kernel(
    const float* __restrict__ x, unsigned short* __restrict__ xhi,
    unsigned short* __restrict__ xlo, int* __restrict__ counter) {
  if (blockIdx.x == 0 && threadIdx.x == 0) *counter = 0;

  const int wave = threadIdx.x >> 6;
  const int lane = threadIdx.x & 63;
  const int l32  = lane & 31;                      // 32 lanes per row
  const int row  = blockIdx.x * 8 + wave * 2 + (lane >> 5);
  const float4 v = ((const float4*)(x + (size_t)row * DIMK))[l32];
  float ss = v.x * v.x + v.y * v.y + v.z * v.z + v.w * v.w;
  #pragma unroll
  for (int s = 1; s < 32; s <<= 1) ss += __shfl_xor(ss, s);  // stays in-half
  const float r = rsqrtf(ss);
  const float a0 = v.x * r, a1 = v.y * r, a2 = v.z * r, a3 = v.w * r;
  ushort4 hi, lo;
  hi.x = bf16_rne(a0); hi.y = bf16_rne(a1);
  hi.z = bf16_rne(a2); hi.w = bf16_rne(a3);
  lo.x = bf16_rne(a0 - __uint_as_float((uint32_t)hi.x << 16));
  lo.y = bf16_rne(a1 - __uint_as_float((uint32_t)hi.y << 16));
  lo.z = bf16_rne(a2 - __uint_as_float((uint32_t)hi.z << 16));
  lo.w = bf16_rne(a3 - __uint_as_float((uint32_t)hi.w << 16));
  ((ushort4*)xhi)[(size_t)row * 32 + l32] = hi;
  ((ushort4*)xlo)[(size_t)row * 32 + l32] = lo;
}

__global__ __launch_bounds__(512, 2) void simloss_kernel(
    const unsigned short* __restrict__ xhi, const unsigned short* __restrict__ xlo,
    float* __restrict__ Col, float* __restrict__ Row) {
  __shared__ unsigned short S[32768];   // 64KB: A stage, B dbuf
  __shared__ float colbuf[2][4][128];   // 4KB, double-buffered col partials

  const int tid  = threadIdx.x;
  const int wave = tid >> 6, lane = tid & 63;
  const int wy = wave & 3, wx = wave >> 2;   // frag grid: 4 row-waves x 2 col-waves
  const int q = lane >> 4, mcol = lane & 15;
  const bool isStage = (wy == 1) || (wy == 2);
  const bool isFlush = (wy == 0);
  const int srank = (wy - 1) + wx * 2;       // 0..3 for stage waves

  const int p  = blockIdx.x >> 4;            // pair index (0..31)
  const int b  = blockIdx.x & 15;
  const int n1 = NT - p;                     // tiles in panel1 (bi=p)
  const int t0 = (b * (NT + 1)) >> 4;        // 65 tiles per pair
  const int t1 = ((b + 1) * (NT + 1)) >> 4;
  const int ntile = t1 - t0;
  const int p2 = NT - 1 - p;                 // panel2 bi

  int cur_bi = (t0 < n1) ? p : p2;

  // ---- A staging (all waves). hi -> S[0..16K), lo -> S[16K..32K) ushorts ----
  auto stageA = [&](int bi) {
    const unsigned short* gh = xhi + (size_t)bi * 128 * DIMK;
    const unsigned short* gl = xlo + (size_t)bi * 128 * DIMK;
    #pragma unroll
    for (int g = 0; g < 4; ++g) {
      const int r  = wave * 16 + g * 4 + (lane >> 4);
      const int sc = (lane & 15) ^ (r & 15);   // XOR swizzle (R6-proven)
      __builtin_amdgcn_global_load_lds((glb_u32*)(gh + (size_t)r * DIMK + sc * 8),
          (lds_u32*)&S[(wave * 16 + g * 4) * 128], 16, 0, 0);
      __builtin_amdgcn_global_load_lds((glb_u32*)(gl + (size_t)r * DIMK + sc * 8),
          (lds_u32*)&S[16384 + (wave * 16 + g * 4) * 128], 16, 0, 0);
    }
  };
  // ---- B staging (stage waves only), 8 instrs each, 32KB tile ----
  auto stageB = [&](int bj, int buf) {
    const unsigned short* gb = xhi + (size_t)bj * 128 * DIMK;
    unsigned short* dst = &S[buf * 16384];
    #pragma unroll
    for (int g = 0; g < 8; ++g) {
      const int r  = srank * 32 + g * 4 + (lane >> 4);
      const int sc = (lane & 15) ^ (r & 15);
      __builtin_amdgcn_global_load_lds((glb_u32*)(gb + (size_t)r * DIMK + sc * 8),
          (lds_u32*)&dst[(srank * 32 + g * 4) * 128], 16, 0, 0);
    }
  };

  short8 Ah[2][4], Al[2][4];
  auto extractA = [&]() {
    #pragma unroll
    for (int fr = 0; fr < 2; ++fr) {
      const int r = wy * 32 + fr * 16 + mcol;
      #pragma unroll
      for (int ks = 0; ks < 4; ++ks) {
        const int pc = (ks * 4 + q) ^ mcol;
        Ah[fr][ks] = *(const short8*)&S[r * 128 + pc * 8];
        Al[fr][ks] = *(const short8*)&S[16384 + r * 128 + pc * 8];
      }
    }
  };

  float rowN[2][4] = {{0.f}};
  // Row flush: unique (b, wx, row) slot -> plain store (NO atomics).
  // Each wave holds one 64-col half of the row sum; slices are summed in
  // finalize (the R15 bug was both wx waves storing to one slot).
  auto flushRows = [&](int bi_) {
    #pragma unroll
    for (int fr = 0; fr < 2; ++fr)
      #pragma unroll
      for (int rg = 0; rg < 4; ++rg) {
        float vn = rowN[fr][rg];
        #pragma unroll
        for (int m2 = 1; m2 < 16; m2 <<= 1) vn += __shfl_xor(vn, m2);
        if (mcol == 0)
          Row[(size_t)(b * 2 + wx) * NR + bi_ * 128 + wy * 32 + fr * 16 + q * 4 + rg] = vn;
      }
  };
  auto zeroRows = [&](int bi_) {
    #pragma unroll
    for (int fr = 0; fr < 2; ++fr)
      #pragma unroll
      for (int rg = 0; rg < 4; ++rg)
        if (mcol == 0)
          Row[(size_t)(b * 2 + wx) * NR + bi_ * 128 + wy * 32 + fr * 16 + q * 4 + rg] = 0.f;
  };

  stageA(cur_bi);
  __syncthreads();            // A staged
  extractA();
  __builtin_amdgcn_s_waitcnt(49279);   // lgkm0: all frag reads done
  __builtin_amdgcn_s_barrier();        // -> S reusable as B buffers
  if (isStage) stageB((t0 < n1) ? p + t0 : p2 + (t0 - n1), 0);

  int pbi = -1, pbj = -1;              // previous tile (deferred col flush)

  for (int tl = 0; tl < ntile; ++tl) {
    const int ix = t0 + tl;
    const int bi = (ix < n1) ? p : p2;
    const int bj = (ix < n1) ? p + ix : p2 + (ix - n1);

    if (bi != cur_bi) {       // panel switch (at most once per block)
      flushRows(cur_bi);
      cur_bi = bi;
      stageA(cur_bi);         // overwrites both B buffers (none pending)
      __syncthreads();
      extractA();
      #pragma unroll
      for (int fr = 0; fr < 2; ++fr)
        #pragma unroll
        for (int rg = 0; rg < 4; ++rg) rowN[fr][rg] = 0.f;
      __builtin_amdgcn_s_waitcnt(49279);
      __builtin_amdgcn_s_barrier();
      if (isStage) stageB(bj, tl & 1);
    }

    // start barrier: stage waves drain their B loads (vm0+lgkm0 = 112);
    // all other waves drain lgkm0 (colbuf write visibility + dbuf safety).
    if (isStage) __builtin_amdgcn_s_waitcnt(112);
    else         __builtin_amdgcn_s_waitcnt(49279);
    __builtin_amdgcn_s_barrier();

    // deferred col flush of PREVIOUS tile: unique (pbi,pbj,col) slot store
    if (isFlush && pbj >= 0 && pbj != pbi) {
      const int col = wx * 64 + lane;
      float sn = 0.f;
      #pragma unroll
      for (int w = 0; w < 4; ++w) sn += colbuf[(tl & 1) ^ 1][w][col];
      Col[(size_t)pbi * NR + pbj * 128 + col] = sn;
    }

    // prefetch next tile's B (same panel only; cross-panel handled above)
    if (tl + 1 < ntile) {
      const int ix2 = ix + 1;
      if ((ix2 < n1) == (ix < n1)) {
        const int bj2 = (ix2 < n1) ? p + ix2 : p2 + (ix2 - n1);
        if (isStage) stageB(bj2, (tl + 1) & 1);
      }
    }

    // ---- compute tile ----
    const unsigned short* Bb = &S[(tl & 1) * 16384];
    f32x4 acc[2][4];
    #pragma unroll
    for (int fr = 0; fr < 2; ++fr)
      #pragma unroll
      for (int fc = 0; fc < 4; ++fc)
        acc[fr][fc] = (f32x4){0.f, 0.f, 0.f, 0.f};
    #pragma unroll
    for (int ks = 0; ks < 4; ++ks) {
      short8 bh[4];
      #pragma unroll
      for (int fc = 0; fc < 4; ++fc) {
        const int rb = wx * 64 + fc * 16 + mcol;
        const int pc = (ks * 4 + q) ^ mcol;
        bh[fc] = *(const short8*)&Bb[rb * 128 + pc * 8];
      }
      #pragma unroll
      for (int fc = 0; fc < 4; ++fc) {
        acc[0][fc] = __builtin_amdgcn_mfma_f32_16x16x32_bf16(Ah[0][ks], bh[fc], acc[0][fc], 0, 0, 0);
        acc[1][fc] = __builtin_amdgcn_mfma_f32_16x16x32_bf16(Ah[1][ks], bh[fc], acc[1][fc], 0, 0, 0);
        acc[0][fc] = __builtin_amdgcn_mfma_f32_16x16x32_bf16(Al[0][ks], bh[fc], acc[0][fc], 0, 0, 0);
        acc[1][fc] = __builtin_amdgcn_mfma_f32_16x16x32_bf16(Al[1][ks], bh[fc], acc[1][fc], 0, 0, 0);
      }
    }

    // ---- epilogue: negatives-only. C layout col = mcol, row = q*4 + rg ----
    float cN[4] = {0.f, 0.f, 0.f, 0.f};
#define EPILOGUE(DIAG_)                                                      \
    {                                                                        \
      _Pragma("unroll")                                                      \
      for (int fr = 0; fr < 2; ++fr) {                                       \
        _Pragma("unroll")                                                    \
        for (int rg = 0; rg < 4; ++rg) {                                     \
          float vn = 0.f;                                                    \
          _Pragma("unroll")                                                  \
          for (int fc = 0; fc < 4; ++fc) {                                   \
            const float s = acc[fr][fc][rg];                                 \
            const float u = fmaxf(fmaf(s, CE1, CE0), 0.f);                   \
            float e = fexp2(u * u);                                          \
            if (DIAG_) {                                                     \
              const int rl = wy * 32 + fr * 16 + q * 4 + rg;                 \
              const int cl = wx * 64 + fc * 16 + mcol;                       \
              e = (rl == cl) ? 0.f : e;                                      \
            }                                                                \
            vn += e;                                                         \
            cN[fc] += e;                                                     \
          }                                                                  \
          rowN[fr][rg] += vn;                                                \
        }                                                                    \
      }                                                                      \
    }
    if (bj == bi) EPILOGUE(true) else EPILOGUE(false)
#undef EPILOGUE

    // col partials: q-reduce then ds_write; flushed at NEXT tile's start
    #pragma unroll
    for (int fc = 0; fc < 4; ++fc) {
      cN[fc] += __shfl_xor(cN[fc], 16);
      cN[fc] += __shfl_xor(cN[fc], 32);
    }
    if (q == 0) {
      #pragma unroll
      for (int fc = 0; fc < 4; ++fc)
        colbuf[tl & 1][wy][wx * 64 + fc * 16 + mcol] = cN[fc];
    }

    pbi = bi; pbj = bj;
  }

  // tail: flush last tile's colbuf, row sums, zero-fill unvisited panel
  __builtin_amdgcn_s_waitcnt(49279);
  __builtin_amdgcn_s_barrier();
  if (isFlush && pbj >= 0 && pbj != pbi) {
    const int col = wx * 64 + lane;
    float sn = 0.f;
    #pragma unroll
    for (int w = 0; w < 4; ++w) sn += colbuf[(ntile - 1) & 1][w][col];
    Col[(size_t)pbi * NR + pbj * 128 + col] = sn;
  }
  flushRows(cur_bi);
  if (!(t0 < n1)) zeroRows(p);    // never visited panel1
  if (!(t1 > n1)) zeroRows(p2);   // never visited panel2
  // kernel end: only plain stores outstanding — fast drain.
}

// ---- finalize: 512 blocks, block == class, 512 threads. Reduces each
// member row's gN from its unique scratch slots (64 Col + 32 Row), computes
// P_i and the e_n over-count, emits log1p terms; per-class partials combined
// fence-free (R4 pattern). ----
__global__ __launch_bounds__(512) void finalize_kernel(
    const unsigned short* __restrict__ xhi, const unsigned short* __restrict__ xlo,
    const int* __restrict__ tgt, const float* __restrict__ Col,
    const float* __restrict__ Row, float* __restrict__ gC,
    int* __restrict__ counter, float* __restrict__ out) {
  __shared__ float Sf[MAXC * 129];   // ~48KB member vectors, stride-129
  __shared__ float Pv[MAXC];
  __shared__ float Ncor[MAXC];
  __shared__ float Gn[MAXC];
  __shared__ int midx[MAXC];
  __shared__ float red[512];
  __shared__ int scnt;
  __shared__ int islast;

  const int tid = threadIdx.x;
  const int me  = (int)blockIdx.x;

  if (tid == 0) scnt = 0;
  if (tid < MAXC) { Pv[tid] = 0.f; Ncor[tid] = 0.f; Gn[tid] = 0.f; }
  __syncthreads();

  // scan tgt (32KB, L2-resident) for members of this class
  const int4* t4 = (const int4*)tgt;
  for (int v = tid; v < NR / 4; v += 512) {   // 4 iterations
    const int4 tv = t4[v];
    const int base = v * 4;
    if (tv.x == me) { const int s_ = atomicAdd(&scnt, 1); if (s_ < MAXC) midx[s_] = base; }
    if (tv.y == me) { const int s_ = atomicAdd(&scnt, 1); if (s_ < MAXC) midx[s_] = base + 1; }
    if (tv.z == me) { const int s_ = atomicAdd(&scnt, 1); if (s_ < MAXC) midx[s_] = base + 2; }
    if (tv.w == me) { const int s_ = atomicAdd(&scnt, 1); if (s_ < MAXC) midx[s_] = base + 3; }
  }
  __syncthreads();
  const int m = (scnt < MAXC) ? scnt : MAXC;

  // load member vectors (hi+lo reconstructed f32); in parallel, reduce each
  // member row's gN from its scratch slots (<=64 Col + 32 Row slots)
  for (int v = tid; v < m * 32; v += 512) {
    const int r = v >> 5, c4 = v & 31;
    const int row = midx[r];
    const ushort4 h = ((const ushort4*)(xhi + (size_t)row * DIMK))[c4];
    const ushort4 l = ((const ushort4*)(xlo + (size_t)row * DIMK))[c4];
    float* d = &Sf[r * 129 + c4 * 4];
    d[0] = __uint_as_float((uint32_t)h.x << 16) + __uint_as_float((uint32_t)l.x << 16);
    d[1] = __uint_as_float((uint32_t)h.y << 16) + __uint_as_float((uint32_t)l.y << 16);
    d[2] = __uint_as_float((uint32_t)h.z << 16) + __uint_as_float((uint32_t)l.z << 16);
    d[3] = __uint_as_float((uint32_t)h.w << 16) + __uint_as_float((uint32_t)l.w << 16);
  }
  for (int v = tid; v < m * 96; v += 512) {
    const int mi = v / 96, sl = v - mi * 96;
    const int r = midx[mi];
    const int pr = r >> 7;
    float val;
    if (sl < 64) val = (sl < pr) ? Col[(size_t)sl * NR + r] : 0.f;
    else         val = Row[(size_t)(sl - 64) * NR + r];
    if (val != 0.f) atomicAdd(&Gn[mi], val);
  }
  __syncthreads();

  // class gram: P_i += ep(s_ij) (j incl. diag, matching ref mask);
  // Ncor_i += en(s_ij) for j != i (the main loop's same-class over-count)
  for (int pr = tid; pr < m * m; pr += 512) {
    const int i = pr / m, j = pr - i * m;
    const float* vi = &Sf[i * 129];
    const float* vj = &Sf[j * 129];
    float s = 0.f;
    #pragma unroll 8
    for (int d = 0; d < 128; ++d) s = fmaf(vi[d], vj[d], s);
    const float ep = __expf(fmaxf(1.25f - s, 0.f) * fmaf(s, 64.f, -48.f));
    atomicAdd(&Pv[i], ep);
    if (i != j) {
      const float u = fmaxf(fmaf(s, CE1, CE0), 0.f);
      atomicAdd(&Ncor[i], fexp2(u * u));
    }
  }
  __syncthreads();

  // per-member loss terms
  float local = 0.f;
  for (int r = tid; r < m; r += 512) {
    local += log1pf(Pv[r] * (Gn[r] - Ncor[r]));
  }
  red[tid] = local;
  __syncthreads();
  for (int s2 = 256; s2 > 0; s2 >>= 1) {
    if (tid < s2) red[tid] += red[tid + s2];
    __syncthreads();
  }
  if (tid == 0) atomicExch(&gC[me], red[0]);   // memory-side, no init needed

  // fence-free rendezvous (R4-proven)
  __builtin_amdgcn_s_waitcnt(0);
  __syncthreads();
  if (tid == 0) islast = (atomicAdd(counter, 1) == NCLS - 1) ? 1 : 0;
  __syncthreads();
  if (islast) {
    red[tid] = atomicAdd(&gC[tid], 0.0f);   // atomic read (cache-bypass)
    __syncthreads();
    for (int s2 = 256; s2 > 0; s2 >>= 1) {
      if (tid < s2) red[tid] += red[tid + s2];
      __syncthreads();
    }
    if (tid == 0) out[0] = red[0] / (float)NR;
  }
}

extern "C" void kernel_launch(void* const* d_in, const int* in_sizes, int n_in,
                              void* d_out, int out_size, void* d_ws, size_t ws_size,
                              hipStream_t stream) {
  const float* x  = (const float*)d_in[0];
  const int* tgt  = (const int*)d_in[1];
  float* out      = (float*)d_out;

  unsigned short* xhi = (unsigned short*)d_ws;
  unsigned short* xlo = xhi + (size_t)NR * DIMK;
  float* Col = (float*)((char*)d_ws + (size_t)NR * DIMK * 4);   // [64][NR]
  float* Row = Col + (size_t)64 * NR;                           // [32][NR]
  float* gC  = Row + (size_t)32 * NR;
  int* counter = (int*)(gC + NCLS);

  normalize_split_kernel<<<NR / 8, 256, 0, stream>>>(x, xhi, xlo, counter);
  simloss_kernel<<<NBLKS, 512, 0, stream>>>(xhi, xlo, Col, Row);
  finalize_kernel<<<NCLS, 512, 0, stream>>>(xhi, xlo, tgt, Col, Row, gC, counter, out);
}